// Round 18
// baseline (478.638 us; speedup 1.0000x reference)
//
#include <hip/hip_runtime.h>
#include <math.h>

#define NQ    10000
#define CD    256
#define KNBR  16
#define NCAND 32
#define CAP   128
#define NT64  158        // 79 tiles x 2 half-tiles of 64 cand rows
#define NPAIR 3160       // 79*80/2 upper-triangle tile pairs
#define MARGIN 2.0f
#define WS_NEED 60098368ull

typedef short bs8 __attribute__((ext_vector_type(8)));
typedef float f32x4 __attribute__((ext_vector_type(4)));
typedef unsigned short u16;
typedef unsigned int u32;
typedef unsigned long long u64;
typedef unsigned short us4 __attribute__((ext_vector_type(4)));

__device__ __forceinline__ float bf2f(u16 u){
  union { u32 i; float f; } c; c.i = ((u32)u) << 16; return c.f;
}
__device__ __forceinline__ u16 f2bf(float f){
  union { float f; u32 i; } c; c.f = f;
  u32 u = c.i;
  u += 0x7fffu + ((u >> 16) & 1u);   // RTNE
  return (u16)(u >> 16);
}
template<int DT>
__device__ __forceinline__ float ldf(const void* p, int i){
  if (DT) return bf2f(((const u16*)p)[i]);
  return ((const float*)p)[i];
}

// ---------------- dtype detect: flag=0 f32, flag=1 bf16 ------------------
__global__ __launch_bounds__(256) void detect_kernel(const u32* __restrict__ xw, int* __restrict__ flag)
{
  __shared__ int cnt;
  if (threadIdx.x == 0) cnt = 0;
  __syncthreads();
  const u32 w = xw[threadIdx.x];
  const int e = (int)((w >> 7) & 0xff);
  if (e >= 120 && e <= 131) atomicAdd(&cnt, 1);
  __syncthreads();
  if (threadIdx.x == 0) flag[0] = (cnt >= 128) ? 1 : 0;
}

// ---------------- x -> bf16 convert + row norms (fused, runtime dt) ------
__global__ __launch_bounds__(256) void cvtn2_kernel(const void* __restrict__ xin, u16* __restrict__ xh,
                                                    float* __restrict__ n2, const int* __restrict__ flag)
{
  const int dt = flag[0];
  const int tid = threadIdx.x, lane = tid & 63;
  const int idx = (blockIdx.x * 256 + tid) * 4;
  float a, b, c, d;
  us4 r;
  if (dt == 0){
    const float4 v = *(const float4*)((const float*)xin + idx);
    a = v.x; b = v.y; c = v.z; d = v.w;
    r[0] = f2bf(a); r[1] = f2bf(b); r[2] = f2bf(c); r[3] = f2bf(d);
  } else {
    r = *(const us4*)((const u16*)xin + idx);
    a = bf2f((u16)r[0]); b = bf2f((u16)r[1]); c = bf2f((u16)r[2]); d = bf2f((u16)r[3]);
  }
  *(us4*)(xh + idx) = r;
  float s = a*a + b*b + c*c + d*d;
  #pragma unroll
  for (int m = 1; m < 64; m <<= 1) s += __shfl_xor(s, m);
  if (lane == 0) n2[idx >> 8] = s;
}

// ---------------- prep: weight transposes + bias bf16 copies -------------
template<int DT>
__device__ __forceinline__ void prep_body(const void* Wq, const void* Wk,
                                          const void* W1, const void* W2,
                                          const void* bq, const void* bk, const void* b1,
                                          u16* wt, u16* w2t, u16* bwb)
{
  const int job = blockIdx.x, n = threadIdx.x;
  if (job == 7){
    bwb[n]       = f2bf(ldf<DT>(bq, n));
    bwb[256 + n] = f2bf(ldf<DT>(bk, n));
    bwb[512 + n] = f2bf(ldf<DT>(b1, n));
    return;
  }
  const void* src; int soff; u16* dst;
  switch (job){
    case 0: src = Wq; soff = 0;     dst = wt;          break;
    case 1: src = Wk; soff = 0;     dst = wt + 65536;  break;
    case 2: src = W1; soff = 65536; dst = wt + 131072; break;
    case 3: src = Wq; soff = 65536; dst = wt + 196608; break;
    case 4: src = Wk; soff = 65536; dst = wt + 262144; break;
    case 5: src = W1; soff = 0;     dst = wt + 327680; break;
    default: src = W2; soff = 0;    dst = w2t;         break;
  }
  for (int c = 0; c < 256; ++c)
    dst[n*256 + c] = f2bf(ldf<DT>(src, soff + c*256 + n));
}
__global__ __launch_bounds__(256) void prep_kernel(const void* __restrict__ Wq, const void* __restrict__ Wk,
                                                   const void* __restrict__ W1, const void* __restrict__ W2,
                                                   const void* __restrict__ bq, const void* __restrict__ bk,
                                                   const void* __restrict__ b1,
                                                   u16* __restrict__ wt, u16* __restrict__ w2t,
                                                   u16* __restrict__ bwb,
                                                   const int* __restrict__ flag)
{
  if (flag[0] == 0) prep_body<0>(Wq, Wk, W1, W2, bq, bk, b1, wt, w2t, bwb);
  else              prep_body<1>(Wq, Wk, W1, W2, bq, bk, b1, wt, w2t, bwb);
}

// ---------------- a2t: A2[s][k] (k=2c+hh -> W2[c][2s+hh]; 512+hh -> b2) --
template<int DT>
__device__ __forceinline__ void a2prep_body(const void* W2, const void* b2, u16* a2t)
{
  const int s = blockIdx.x;
  const int c = threadIdx.x;
  a2t[s*544 + 2*c]     = f2bf(ldf<DT>(W2, c*256 + 2*s));
  a2t[s*544 + 2*c + 1] = f2bf(ldf<DT>(W2, c*256 + 2*s + 1));
  if (c < 2)        a2t[s*544 + 512 + c] = f2bf(ldf<DT>(b2, 2*s + c));
  else if (c < 32)  a2t[s*544 + 512 + c] = 0;
}
__global__ __launch_bounds__(256) void a2prep_kernel(const void* __restrict__ W2, const void* __restrict__ b2,
                                                     u16* __restrict__ a2t, const int* __restrict__ flag)
{
  if (flag[0] == 0) a2prep_body<0>(W2, b2, a2t);
  else              a2prep_body<1>(W2, b2, a2t);
}

// ---------------- zero the dump / tile counters --------------------------
__global__ __launch_bounds__(256) void zero_kernel(int* __restrict__ g, int* __restrict__ tcnt)
{
  const int i = blockIdx.x * 256 + threadIdx.x;
  if (i < NQ) g[i] = 0;
  if (i < NT64) tcnt[i] = 0;
}

// ---------------- projections as tiled GEMM (knn_gemm template) ----------
__global__ __launch_bounds__(256) void pgemm_kernel(const u16* __restrict__ xh,
                                                    const u16* __restrict__ wt,
                                                    const u16* __restrict__ bwb,
                                                    u16* __restrict__ SP, u16* __restrict__ DP)
{
  __shared__ u16 cta[128 * 256];   // 64 KB
  const int tid = threadIdx.x, wave = tid >> 6, lane = tid & 63;
  const int l15 = lane & 15, lq = lane >> 4;
  const int qg = wave & 1, cg = wave >> 1;
  const int I0 = blockIdx.x * 128;

  {
    const int rloc = tid >> 5;
    const int cby  = (tid & 31) * 16;
    const int wby  = cby ^ ((rloc & 7) << 4);
    #pragma unroll
    for (int i = 0; i < 16; ++i){
      int grow = I0 + i * 8 + rloc;
      if (grow > NQ - 1) grow = NQ - 1;
      const uint4 v = *(const uint4*)(xh + grow * 256 + (cby >> 1));
      *(uint4*)((char*)cta + (i * 8 + rloc) * 512 + wby) = v;
    }
  }
  __syncthreads();

  const int crb = I0 + cg * 64 + lq * 4;

  #pragma unroll 1
  for (int jp = 0; jp < 2; ++jp){
    const int J0 = (blockIdx.y * 2 + jp) * 128;
    const int q0 = J0 + qg * 64;

    f32x4 acc[4][4];
    #pragma unroll
    for (int cf = 0; cf < 4; ++cf)
      #pragma unroll
      for (int qf = 0; qf < 4; ++qf)
        acc[cf][qf] = (f32x4){0.f, 0.f, 0.f, 0.f};

    #pragma unroll
    for (int ks = 0; ks < 8; ++ks){
      bs8 qv[4];
      #pragma unroll
      for (int qf = 0; qf < 4; ++qf){
        const int wc = q0 + qf * 16 + l15;
        qv[qf] = *(const bs8*)(wt + wc * 256 + ks * 32 + lq * 8);
      }
      bs8 cv[4];
      #pragma unroll
      for (int cf = 0; cf < 4; ++cf){
        const int row = cg * 64 + cf * 16 + l15;
        const int cby = (ks * 64 + lq * 16) ^ ((l15 & 7) << 4);
        cv[cf] = *(const bs8*)((const char*)cta + row * 512 + cby);
      }
      #pragma unroll
      for (int cf = 0; cf < 4; ++cf)
        #pragma unroll
        for (int qf = 0; qf < 4; ++qf)
          acc[cf][qf] = __builtin_amdgcn_mfma_f32_16x16x32_bf16(cv[cf], qv[qf], acc[cf][qf], 0, 0, 0);
    }

    #pragma unroll
    for (int qf = 0; qf < 4; ++qf){
      const int c = q0 + qf * 16 + l15;
      const float bias = (c >= 768) ? bf2f(bwb[c - 768]) : 0.f;
      #pragma unroll
      for (int cf = 0; cf < 4; ++cf){
        #pragma unroll
        for (int q = 0; q < 4; ++q){
          const int node = crb + cf * 16 + q;
          if (node < NQ){
            const u16 v = f2bf(acc[cf][qf][q] + bias);
            if (c < 768) SP[node * 768 + c] = v;
            else         DP[node * 768 + (c - 768)] = v;
          }
        }
      }
    }
  }
}

// ---------------- kNN Gram PASS A: one (I,J) pair per block --------------
// Closed-form pair decode; qv/n2 prefetched BEFORE the barrier so their L2
// latency hides under the stage drain (LDS caps occupancy at 2 blocks/CU,
// so the extra VGPR live range is free).
__global__ __launch_bounds__(256) void knn_gemm_kernel(
    const u16* __restrict__ xh, const float* __restrict__ n2,
    float* __restrict__ minD)
{
  __shared__ u16 cta[128 * 256];   // 64 KB
  const int tid = threadIdx.x, wave = tid >> 6, lane = tid & 63;
  const int l15 = lane & 15, lq = lane >> 4;
  const int qg = wave & 1, cg = wave >> 1;

  const int p = blockIdx.x;
  int I = (int)((159.0 - sqrt(25281.0 - 8.0 * (double)p)) * 0.5);
  if (I < 0) I = 0;
  while (79 * I - (I * (I - 1)) / 2 > p) --I;
  while (79 * (I + 1) - ((I + 1) * I) / 2 <= p) ++I;
  const int J = I + (p - (79 * I - (I * (I - 1)) / 2));
  const int I0 = I * 128, J0 = J * 128;

  // ---- stage A-tile to LDS (swizzled) ----
  {
    const int rloc = tid >> 5;
    const int cby  = (tid & 31) * 16;
    const int wby  = cby ^ ((rloc & 7) << 4);
    #pragma unroll
    for (int i = 0; i < 16; ++i){
      int grow = I0 + i * 8 + rloc;
      if (grow > NQ - 1) grow = NQ - 1;
      const uint4 v = *(const uint4*)(xh + grow * 256 + (cby >> 1));
      *(uint4*)((char*)cta + (i * 8 + rloc) * 512 + wby) = v;
    }
  }

  const int crb = I0 + cg * 64 + lq * 4;
  const int q0 = J0 + qg * 64;

  // ---- prefetch qv + n2 BEFORE barrier (independent of LDS) ----
  bs8 qv[8][4];
  #pragma unroll
  for (int ks = 0; ks < 8; ++ks)
    #pragma unroll
    for (int qf = 0; qf < 4; ++qf){
      int qr = q0 + qf * 16 + l15; if (qr > NQ - 1) qr = NQ - 1;
      qv[ks][qf] = *(const bs8*)(xh + qr * 256 + ks * 32 + lq * 8);
    }
  float n2v[4][4];
  #pragma unroll
  for (int cf = 0; cf < 4; ++cf)
    #pragma unroll
    for (int q = 0; q < 4; ++q){
      int r = crb + cf * 16 + q; if (r > NQ - 1) r = NQ - 1;
      n2v[cf][q] = n2[r];
    }
  float n2c[4];
  #pragma unroll
  for (int qf = 0; qf < 4; ++qf){
    int c = q0 + qf * 16 + l15; if (c > NQ - 1) c = NQ - 1;
    n2c[qf] = n2[c];
  }

  __syncthreads();

  f32x4 acc[4][4];
  #pragma unroll
  for (int cf = 0; cf < 4; ++cf)
    #pragma unroll
    for (int qf = 0; qf < 4; ++qf)
      acc[cf][qf] = (f32x4){0.f, 0.f, 0.f, 0.f};

  #pragma unroll
  for (int ks = 0; ks < 8; ++ks){
    bs8 cv[4];
    #pragma unroll
    for (int cf = 0; cf < 4; ++cf){
      const int row = cg * 64 + cf * 16 + l15;
      const int cby = (ks * 64 + lq * 16) ^ ((l15 & 7) << 4);
      cv[cf] = *(const bs8*)((const char*)cta + row * 512 + cby);
    }
    #pragma unroll
    for (int cf = 0; cf < 4; ++cf)
      #pragma unroll
      for (int qf = 0; qf < 4; ++qf)
        acc[cf][qf] = __builtin_amdgcn_mfma_f32_16x16x32_bf16(cv[cf], qv[ks][qf], acc[cf][qf], 0, 0, 0);
  }

  // normal: min over rows -> minD[I-half][col]
  #pragma unroll
  for (int qf = 0; qf < 4; ++qf){
    const int qc = q0 + qf * 16 + l15;
    float m = __builtin_inff();
    #pragma unroll
    for (int cf = 0; cf < 4; ++cf)
      #pragma unroll
      for (int q = 0; q < 4; ++q){
        const int r = crb + cf * 16 + q;
        const float dd = n2v[cf][q] - 2.f * acc[cf][qf][q];
        const bool ok = (r < NQ) && (r != qc);
        m = fminf(m, ok ? dd : __builtin_inff());
      }
    m = fminf(m, __shfl_xor(m, 16));
    m = fminf(m, __shfl_xor(m, 32));
    if (lane < 16){
      const int qs = q0 + qf * 16 + lane;
      if (qs < NQ) minD[(I * 2 + cg) * NQ + qs] = m;
    }
  }
  // transposed (off-diagonal only): min over cols -> minD[J-half][row]
  if (I != J){
    #pragma unroll
    for (int cf = 0; cf < 4; ++cf)
      #pragma unroll
      for (int q = 0; q < 4; ++q){
        float m = __builtin_inff();
        #pragma unroll
        for (int qf = 0; qf < 4; ++qf){
          const int c = q0 + qf * 16 + l15;
          const float v = n2c[qf] - 2.f * acc[cf][qf][q];
          m = fminf(m, (c < NQ) ? v : __builtin_inff());
        }
        m = fminf(m, __shfl_xor(m, 1));
        m = fminf(m, __shfl_xor(m, 2));
        m = fminf(m, __shfl_xor(m, 4));
        m = fminf(m, __shfl_xor(m, 8));
        const int r = crb + cf * 16 + q;
        if (l15 == 0 && r < NQ) minD[(J * 2 + qg) * NQ + r] = m;
      }
  }
}

// ---------------- tau: 16th-smallest tile-min + margin -------------------
__global__ __launch_bounds__(256) void knn_tau_kernel(const float* __restrict__ minD,
                                                      float* __restrict__ tauP)
{
  const int q = blockIdx.x * 256 + threadIdx.x;
  if (q >= NQ) return;
  float ld[16];
  #pragma unroll
  for (int s = 0; s < 16; ++s) ld[s] = __builtin_inff();
  for (int t = 0; t < NT64; ++t){
    float v = minD[t * NQ + q];
    if (v < ld[15]){
      #pragma unroll
      for (int s = 0; s < 16; ++s){
        const bool cmp = v < ld[s];
        const float tv = ld[s];
        ld[s] = cmp ? v : tv;
        v = cmp ? tv : v;
      }
    }
  }
  tauP[q] = ld[15] + MARGIN;
}

// ---------------- build per-tile query lists (wave-per-tile, NO atomics) -
__global__ __launch_bounds__(256) void listbuild_kernel(const float* __restrict__ minD,
                                                        const float* __restrict__ tauP,
                                                        int* __restrict__ tcnt,
                                                        int* __restrict__ qlist)
{
  const int wave = threadIdx.x >> 6, lane = threadIdx.x & 63;
  const int t = blockIdx.x * 4 + wave;
  if (t >= NT64) return;
  const float* row = minD + (size_t)t * NQ;
  int base = 0;
  #pragma unroll 1
  for (int c = 0; c < 157; ++c){
    const int q = c * 64 + lane;
    const bool f = (q < NQ) && (row[q] < tauP[q]);
    const u64 mask = __ballot(f);
    if (f){
      const int off = (int)__popcll(mask & ((1ull << lane) - 1ull));
      qlist[t * NQ + base + off] = q;
    }
    base += (int)__popcll(mask);
  }
  if (lane == 0) tcnt[t] = base;
}

// ---------------- PASS C replacement: tile-centric pruned scan -----------
__global__ __launch_bounds__(256) void knn_scan_kernel(
    const u16* __restrict__ xh, const float* __restrict__ n2,
    const float* __restrict__ tauP, const int* __restrict__ tcnt,
    const int* __restrict__ qlist, int* __restrict__ gcnt,
    u64* __restrict__ candP)
{
  __shared__ u16 cta[64 * 256];   // 32 KB
  const int t = blockIdx.x;
  const int chunk = blockIdx.y;
  const int tid = threadIdx.x, wave = tid >> 6, lane = tid & 63;
  const int l15 = lane & 15, lq = lane >> 4;
  const int I0 = t * 64;

  {
    const int rloc = tid >> 5;
    const int cby  = (tid & 31) * 16;
    const int wby  = cby ^ ((rloc & 7) << 4);
    #pragma unroll
    for (int i = 0; i < 8; ++i){
      int grow = I0 + i * 8 + rloc;
      if (grow > NQ - 1) grow = NQ - 1;
      const uint4 v = *(const uint4*)(xh + grow * 256 + (cby >> 1));
      *(uint4*)((char*)cta + (i * 8 + rloc) * 512 + wby) = v;
    }
  }
  __syncthreads();

  float n2v[4][4];
  #pragma unroll
  for (int cf = 0; cf < 4; ++cf)
    #pragma unroll
    for (int q = 0; q < 4; ++q){
      int r = I0 + cf * 16 + lq * 4 + q; if (r > NQ - 1) r = NQ - 1;
      n2v[cf][q] = n2[r];
    }

  const int cnt = tcnt[t];
  const int ngr = (cnt + 15) >> 4;

  #pragma unroll 1
  for (int gi = chunk * 4 + wave; gi < ngr; gi += 32){
    const int qi = gi * 16 + l15;
    const bool qok = qi < cnt;
    const int qc = qok ? qlist[t * NQ + qi] : 0;

    bs8 qv[8];
    #pragma unroll
    for (int ks = 0; ks < 8; ++ks)
      qv[ks] = *(const bs8*)(xh + qc * 256 + ks * 32 + lq * 8);

    f32x4 acc[4];
    #pragma unroll
    for (int cf = 0; cf < 4; ++cf) acc[cf] = (f32x4){0.f, 0.f, 0.f, 0.f};

    #pragma unroll
    for (int ks = 0; ks < 8; ++ks){
      const int cby = (ks * 64 + lq * 16) ^ ((l15 & 7) << 4);
      #pragma unroll
      for (int cf = 0; cf < 4; ++cf){
        const bs8 cv = *(const bs8*)((const char*)cta + (cf * 16 + l15) * 512 + cby);
        acc[cf] = __builtin_amdgcn_mfma_f32_16x16x32_bf16(cv, qv[ks], acc[cf], 0, 0, 0);
      }
    }

    const float tq = qok ? tauP[qc] : -__builtin_inff();
    #pragma unroll
    for (int cf = 0; cf < 4; ++cf){
      #pragma unroll
      for (int q = 0; q < 4; ++q){
        const int r = I0 + cf * 16 + lq * 4 + q;
        const float dd = n2v[cf][q] - 2.f * acc[cf][q];
        const bool dump = qok && (r < NQ) && (r != qc) && (dd < tq);
        if (dump){
          const int pos = atomicAdd(gcnt + qc, 1);
          if (pos < CAP)
            candP[qc * CAP + pos] =
                (((u64)__float_as_uint(dd + 1024.f)) << 32) | (u32)r;
        }
      }
    }
  }
}

// ---------------- select top-32 of dumped candidates ---------------------
__global__ __launch_bounds__(256) void select32_kernel(const u64* __restrict__ candP,
                                                       const int* __restrict__ gcnt,
                                                       int* __restrict__ cand,
                                                       int* __restrict__ ccnt)
{
  __shared__ u64 sl[4][CAP];
  const int tid = threadIdx.x, wave = tid >> 6, lane = tid & 63;
  const int q = blockIdx.x * 4 + wave;
  int cnt = gcnt[q]; if (cnt > CAP) cnt = CAP;
  const u64* src = candP + (size_t)q * CAP;
  for (int c = lane; c < cnt; c += 64) sl[wave][c] = src[c];
  __syncthreads();
  for (int c = lane; c < cnt; c += 64){
    const u64 me = sl[wave][c];
    int rank = 0;
    for (int o = 0; o < cnt; ++o){
      const u64 ov = sl[wave][o];
      rank += (ov < me || (ov == me && o < c)) ? 1 : 0;
    }
    if (rank < NCAND) cand[q * NCAND + rank] = (int)(me & 0xffffffffu);
  }
  if (lane == 0) ccnt[q] = (cnt < NCAND) ? cnt : NCAND;
}

// ---------------- exact rescore of <=32 candidates -> top-16 -------------
template<int DT>
__device__ __forceinline__ void rescore_body(const void* x, const float* n2,
                                             const int* cand, const int* ccnt, int* knn)
{
  const int tid = threadIdx.x, wave = tid >> 6, lane = tid & 63;
  const int i = blockIdx.x * 4 + wave;
  const int base = i * CD + lane * 4;
  float xi0, xi1, xi2, xi3;
  if (DT == 0){
    const float4 v = *(const float4*)((const float*)x + base);
    xi0 = v.x; xi1 = v.y; xi2 = v.z; xi3 = v.w;
  } else {
    const u32* p = (const u32*)x + (base >> 1);
    const u32 w0 = p[0], w1 = p[1];
    xi0 = bf2f((u16)(w0 & 0xffff)); xi1 = bf2f((u16)(w0 >> 16));
    xi2 = bf2f((u16)(w1 & 0xffff)); xi3 = bf2f((u16)(w1 >> 16));
  }
  const float n2i = n2[i];
  const int cc = ccnt[i];
  const int cown = lane & 31;
  float myd = __builtin_inff(); int myi = NQ + lane;
  for (int c = 0; c < NCAND; ++c){
    const int jr = cand[i * NCAND + c];
    const int j = (c < cc) ? jr : 0;
    const int jb = j * CD + lane * 4;
    float a0, a1, a2, a3;
    if (DT == 0){
      const float4 v = *(const float4*)((const float*)x + jb);
      a0 = v.x; a1 = v.y; a2 = v.z; a3 = v.w;
    } else {
      const u32* p = (const u32*)x + (jb >> 1);
      const u32 w0 = p[0], w1 = p[1];
      a0 = bf2f((u16)(w0 & 0xffff)); a1 = bf2f((u16)(w0 >> 16));
      a2 = bf2f((u16)(w1 & 0xffff)); a3 = bf2f((u16)(w1 >> 16));
    }
    float pdt = xi0*a0 + xi1*a1 + xi2*a2 + xi3*a3;
    #pragma unroll
    for (int m = 1; m < 64; m <<= 1) pdt += __shfl_xor(pdt, m);
    const float d = n2i + n2[j] - 2.f * pdt;
    if (c == cown && c < cc){ myd = d; myi = j; }
  }
  int rank = 0;
  #pragma unroll
  for (int m = 1; m < NCAND; ++m){
    int oc = cown + m; if (oc >= NCAND) oc -= NCAND;
    const float od = __shfl(myd, oc);
    const int   oi = __shfl(myi, oc);
    rank += (od < myd || (od == myd && oi < myi)) ? 1 : 0;
  }
  if (lane < NCAND && rank < KNBR) knn[i * KNBR + rank] = myi;
}
__global__ __launch_bounds__(256) void rescore_kernel(const void* __restrict__ x, const float* __restrict__ n2,
                                                      const int* __restrict__ cand, const int* __restrict__ ccnt,
                                                      int* __restrict__ knn,
                                                      const int* __restrict__ flag)
{
  if (flag[0] == 0) rescore_body<0>(x, n2, cand, ccnt, knn);
  else              rescore_body<1>(x, n2, cand, ccnt, knn);
}

// ---------------- edge2: block-per-node, LDS-staged ----------------------
template<int DT>
__device__ __forceinline__ void edge2_body(const void* x, const u16* SP, const u16* DP,
                                           const int* knn, u16* TB0, u16* TB1,
                                           char* rows, float (*ewb)[4])
{
  const int tid = threadIdx.x;
  const int i = blockIdx.x;

  {
    const int e = tid >> 4, six = tid & 15;
    const int j = knn[i * KNBR + e];
    const int swz = (e & 7) << 4;
    #pragma unroll
    for (int ch = 0; ch < 6; ++ch){
      const uint4 v = *(const uint4*)(SP + j * 768 + ch * 128 + six * 8);
      *(uint4*)(rows + e * 1536 + ((ch * 256 + six * 16) ^ swz)) = v;
    }
    if (tid < 96){
      const uint4 v = *(const uint4*)(DP + i * 768 + tid * 8);
      *(uint4*)(rows + 16 * 1536 + tid * 16) = v;
    }
  }
  __syncthreads();

  {
    const int w = tid >> 6, e = (tid >> 2) & 15, cs = tid & 3;
    const int hh = w >> 1, g = w & 1;
    const int swz = (e & 7) << 4;
    const char* er = rows + e * 1536;
    const char* dr = rows + 16 * 1536;
    float dot = 0.f;
    #pragma unroll
    for (int z = 0; z < 4; ++z){
      const int qoff = hh * 256 + cs * 64 + z * 16;
      const int koff = 512 + g * 256 + cs * 64 + z * 16;
      const bs8 sq = *(const bs8*)(er + (qoff ^ swz));
      const bs8 dq = *(const bs8*)(dr + qoff);
      const bs8 sk = *(const bs8*)(er + (koff ^ swz));
      const bs8 dk = *(const bs8*)(dr + koff);
      #pragma unroll
      for (int m = 0; m < 8; ++m){
        const float Q = bf2f((u16)sq[m]) + bf2f((u16)dq[m]);
        const float K = bf2f((u16)sk[m]) + bf2f((u16)dk[m]);
        dot += Q * K;
      }
    }
    dot += __shfl_xor(dot, 1);
    dot += __shfl_xor(dot, 2);
    if (cs == 0) ewb[e][w] = dot * 0.0625f;
  }
  __syncthreads();

  if (tid < 4){
    float S = 0.f;
    #pragma unroll
    for (int e = 0; e < 16; ++e) S += ewb[e][tid];
    const int hh = tid >> 1, g = tid & 1;
    (g ? TB1 : TB0)[i * 544 + 512 + hh] = f2bf(S);
  } else if (tid < 34){
    TB0[i * 544 + 510 + tid] = 0;
    TB1[i * 544 + 510 + tid] = 0;
  }

  {
    const int c = tid;
    const float A1c = bf2f(*(const u16*)(rows + 16 * 1536 + 1024 + 2 * c));
    const float xi = ldf<DT>(x, i * 256 + c);
    float T0 = 0.f, T1 = 0.f, T2 = 0.f, T3 = 0.f;
    #pragma unroll
    for (int e = 0; e < 16; ++e){
      const float4 e4 = *(const float4*)&ewb[e][0];
      const float B1 = bf2f(*(const u16*)(rows + e * 1536 + ((1024 + 2 * c) ^ ((e & 7) << 4))));
      const float h = fmaxf(A1c + B1, 0.f) + xi;
      T0 += h * e4.x; T1 += h * e4.y; T2 += h * e4.z; T3 += h * e4.w;
    }
    *(u32*)(TB0 + i * 544 + 2 * c) = (u32)f2bf(T0) | ((u32)f2bf(T2) << 16);
    *(u32*)(TB1 + i * 544 + 2 * c) = (u32)f2bf(T1) | ((u32)f2bf(T3) << 16);
  }
}
__global__ __launch_bounds__(256) void edge2_kernel(
    const void* __restrict__ x, const u16* __restrict__ SP, const u16* __restrict__ DP,
    const int* __restrict__ knn, u16* __restrict__ TB0, u16* __restrict__ TB1,
    const int* __restrict__ flag)
{
  __shared__ char rows[17 * 1536];
  __shared__ float ewb[16][4];
  if (flag[0] == 0) edge2_body<0>(x, SP, DP, knn, TB0, TB1, rows, ewb);
  else              edge2_body<1>(x, SP, DP, knn, TB0, TB1, rows, ewb);
}

// ---------------- fgemm: OUT_g = TBg @ A2^T (incl. bias-S, /16) ----------
template<int DT>
__device__ __forceinline__ void fgemm_body(const u16* TB0, const u16* TB1,
                                           const u16* a2t, void* out)
{
  const int tid = threadIdx.x, wave = tid >> 6, lane = tid & 63;
  const int l15 = lane & 15, lq = lane >> 4;
  const int I0 = blockIdx.x * 64;
  const int s0 = blockIdx.y * 64;
  const int g = wave & 1, nh = wave >> 1;
  const u16* TB = g ? TB1 : TB0;
  const int nodeb = I0 + nh * 32;

  f32x4 acc[2][4];
  #pragma unroll
  for (int cf = 0; cf < 2; ++cf)
    #pragma unroll
    for (int qf = 0; qf < 4; ++qf) acc[cf][qf] = (f32x4){0.f, 0.f, 0.f, 0.f};

  #pragma unroll
  for (int ks = 0; ks < 17; ++ks){
    bs8 av[2], bv[4];
    #pragma unroll
    for (int cf = 0; cf < 2; ++cf){
      int nr = nodeb + cf * 16 + l15; if (nr > NQ - 1) nr = NQ - 1;
      av[cf] = *(const bs8*)(TB + nr * 544 + ks * 32 + lq * 8);
    }
    #pragma unroll
    for (int qf = 0; qf < 4; ++qf)
      bv[qf] = *(const bs8*)(a2t + (s0 + qf * 16 + l15) * 544 + ks * 32 + lq * 8);
    #pragma unroll
    for (int cf = 0; cf < 2; ++cf)
      #pragma unroll
      for (int qf = 0; qf < 4; ++qf)
        acc[cf][qf] = __builtin_amdgcn_mfma_f32_16x16x32_bf16(av[cf], bv[qf], acc[cf][qf], 0, 0, 0);
  }

  #pragma unroll
  for (int cf = 0; cf < 2; ++cf)
    #pragma unroll
    for (int qf = 0; qf < 4; ++qf){
      const int scol = s0 + qf * 16 + l15;
      #pragma unroll
      for (int q = 0; q < 4; ++q){
        const int node = nodeb + cf * 16 + lq * 4 + q;
        if (node < NQ){
          const float val = acc[cf][qf][q] * 0.0625f;
          if (DT == 0) ((float*)out)[node * 256 + 2 * scol + g] = val;
          else         ((u16*)out)[node * 256 + 2 * scol + g] = f2bf(val);
        }
      }
    }
}
__global__ __launch_bounds__(256) void fgemm_kernel(const u16* __restrict__ TB0, const u16* __restrict__ TB1,
                                                    const u16* __restrict__ a2t, void* __restrict__ out,
                                                    const int* __restrict__ flag)
{
  if (flag[0] == 0) fgemm_body<0>(TB0, TB1, a2t, out);
  else              fgemm_body<1>(TB0, TB1, a2t, out);
}

extern "C" void kernel_launch(void* const* d_in, const int* in_sizes, int n_in,
                              void* d_out, int out_size, void* d_ws, size_t ws_size,
                              hipStream_t stream)
{
  const void* x  = d_in[0];
  const void* W1 = d_in[1];
  const void* b1 = d_in[2];
  const void* W2 = d_in[3];
  const void* b2 = d_in[4];
  const void* Wq = d_in[5];
  const void* bq = d_in[6];
  const void* Wk = d_in[7];
  const void* bk = d_in[8];

  char* ws = (char*)d_ws;
  int*   flag  = (int*)ws;                    // 64
  u16*   xh    = (u16*)(ws + 64);             // 5,120,000
  u16*   wt    = (u16*)(ws + 5120064);        // 786,432
  u16*   a2t   = (u16*)(ws + 5906496);        // 139,264
  u16*   w2t   = (u16*)(ws + 6045760);        // 131,072 (unused, kept for layout)
  u16*   bwb   = (u16*)(ws + 6176832);        // 1,536
  float* n2    = (float*)(ws + 6178368);      // 40,000
  float* tauP  = (float*)(ws + 6218368);      // 40,000
  int*   gcnt  = (int*)(ws + 6258368);        // 40,000
  int*   ccnt  = (int*)(ws + 6298368);        // 40,000
  int*   knn   = (int*)(ws + 6338368);        // 640,000
  int*   cand  = (int*)(ws + 6978368);        // 1,280,000
  float* minD  = (float*)(ws + 8258368);      // 6,320,000 (window with candP)
  u64*   candP = (u64*)(ws + 8258368);        // 10,240,000
  u16*   SP    = (u16*)(ws + 18498368);       // 15,360,000
  u16*   DP    = (u16*)(ws + 33858368);       // 15,360,000
  u16*   TB0   = (u16*)(ws + 6978368);        // 10,880,000 (aliases cand+candP, dead by then)
  int*   tcnt  = (int*)(ws + 49218368);       // 640 (TB1 region; dead before edge2)
  int*   qlist = (int*)(ws + 49219008);       // 158*10000*4 = 6,320,000
  u16*   TB1   = (u16*)(ws + 49218368);       // 10,880,000 (edge2 phase only)
  // total (big path): 60,098,368 bytes
  (void)w2t; (void)ws_size;

  detect_kernel<<<1, 256, 0, stream>>>((const u32*)x, flag);

  cvtn2_kernel<<<2500, 256, 0, stream>>>(x, xh, n2, flag);
  prep_kernel<<<8, 256, 0, stream>>>(Wq, Wk, W1, W2, bq, bk, b1, wt, (u16*)(ws + 6045760), bwb, flag);
  a2prep_kernel<<<128, 256, 0, stream>>>(W2, b2, a2t, flag);
  zero_kernel<<<40, 256, 0, stream>>>(gcnt, tcnt);

  pgemm_kernel<<<dim3(79, 6), 256, 0, stream>>>(xh, wt, bwb, SP, DP);

  knn_gemm_kernel<<<NPAIR, 256, 0, stream>>>(xh, n2, minD);
  knn_tau_kernel<<<40, 256, 0, stream>>>(minD, tauP);
  listbuild_kernel<<<40, 256, 0, stream>>>(minD, tauP, tcnt, qlist);
  knn_scan_kernel<<<dim3(NT64, 8), 256, 0, stream>>>(xh, n2, tauP, tcnt, qlist, gcnt, candP);
  select32_kernel<<<2500, 256, 0, stream>>>(candP, gcnt, cand, ccnt);

  rescore_kernel<<<2500, 256, 0, stream>>>(x, n2, cand, ccnt, knn, flag);

  edge2_kernel<<<10000, 256, 0, stream>>>(x, SP, DP, knn, TB0, TB1, flag);
  fgemm_kernel<<<dim3(157, 2), 256, 0, stream>>>(TB0, TB1, a2t, d_out, flag);
}

// Round 19
// 433.765 us; speedup vs baseline: 1.1035x; 1.1035x over previous
//
#include <hip/hip_runtime.h>

#define NQ    10000
#define CD    256
#define KNBR  16
#define NCAND 32
#define CAP   128
#define NT64  158        // 79 tiles x 2 half-tiles of 64 cand rows
#define NPAIR 3160       // 79*80/2 upper-triangle tile pairs
#define MARGIN 2.0f

typedef short bs8 __attribute__((ext_vector_type(8)));
typedef float f32x4 __attribute__((ext_vector_type(4)));
typedef unsigned short u16;
typedef unsigned int u32;
typedef unsigned long long u64;
typedef unsigned short us4 __attribute__((ext_vector_type(4)));

__device__ __forceinline__ float bf2f(u16 u){
  union { u32 i; float f; } c; c.i = ((u32)u) << 16; return c.f;
}
__device__ __forceinline__ u16 f2bf(float f){
  union { float f; u32 i; } c; c.f = f;
  u32 u = c.i;
  u += 0x7fffu + ((u >> 16) & 1u);   // RTNE
  return (u16)(u >> 16);
}
template<int DT>
__device__ __forceinline__ float ldf(const void* p, int i){
  if (DT) return bf2f(((const u16*)p)[i]);
  return ((const float*)p)[i];
}

// ---------------- dtype detect: flag=0 f32, flag=1 bf16 ------------------
__global__ __launch_bounds__(256) void detect_kernel(const u32* __restrict__ xw, int* __restrict__ flag)
{
  __shared__ int cnt;
  if (threadIdx.x == 0) cnt = 0;
  __syncthreads();
  const u32 w = xw[threadIdx.x];
  const int e = (int)((w >> 7) & 0xff);
  if (e >= 120 && e <= 131) atomicAdd(&cnt, 1);
  __syncthreads();
  if (threadIdx.x == 0) flag[0] = (cnt >= 128) ? 1 : 0;
}

// ---------------- x -> bf16 convert + row norms (fused, runtime dt) ------
__global__ __launch_bounds__(256) void cvtn2_kernel(const void* __restrict__ xin, u16* __restrict__ xh,
                                                    float* __restrict__ n2, const int* __restrict__ flag)
{
  const int dt = flag[0];
  const int tid = threadIdx.x, lane = tid & 63;
  const int idx = (blockIdx.x * 256 + tid) * 4;
  float a, b, c, d;
  us4 r;
  if (dt == 0){
    const float4 v = *(const float4*)((const float*)xin + idx);
    a = v.x; b = v.y; c = v.z; d = v.w;
    r[0] = f2bf(a); r[1] = f2bf(b); r[2] = f2bf(c); r[3] = f2bf(d);
  } else {
    r = *(const us4*)((const u16*)xin + idx);
    a = bf2f((u16)r[0]); b = bf2f((u16)r[1]); c = bf2f((u16)r[2]); d = bf2f((u16)r[3]);
  }
  *(us4*)(xh + idx) = r;
  float s = a*a + b*b + c*c + d*d;
  #pragma unroll
  for (int m = 1; m < 64; m <<= 1) s += __shfl_xor(s, m);
  if (lane == 0) n2[idx >> 8] = s;
}

// ---------------- prep: weight transposes + bias bf16 copies -------------
template<int DT>
__device__ __forceinline__ void prep_body(const void* Wq, const void* Wk,
                                          const void* W1, const void* W2,
                                          const void* bq, const void* bk, const void* b1,
                                          u16* wt, u16* w2t, u16* bwb)
{
  const int job = blockIdx.x, n = threadIdx.x;
  if (job == 7){
    bwb[n]       = f2bf(ldf<DT>(bq, n));
    bwb[256 + n] = f2bf(ldf<DT>(bk, n));
    bwb[512 + n] = f2bf(ldf<DT>(b1, n));
    return;
  }
  const void* src; int soff; u16* dst;
  switch (job){
    case 0: src = Wq; soff = 0;     dst = wt;          break;
    case 1: src = Wk; soff = 0;     dst = wt + 65536;  break;
    case 2: src = W1; soff = 65536; dst = wt + 131072; break;
    case 3: src = Wq; soff = 65536; dst = wt + 196608; break;
    case 4: src = Wk; soff = 65536; dst = wt + 262144; break;
    case 5: src = W1; soff = 0;     dst = wt + 327680; break;
    default: src = W2; soff = 0;    dst = w2t;         break;
  }
  for (int c = 0; c < 256; ++c)
    dst[n*256 + c] = f2bf(ldf<DT>(src, soff + c*256 + n));
}
__global__ __launch_bounds__(256) void prep_kernel(const void* __restrict__ Wq, const void* __restrict__ Wk,
                                                   const void* __restrict__ W1, const void* __restrict__ W2,
                                                   const void* __restrict__ bq, const void* __restrict__ bk,
                                                   const void* __restrict__ b1,
                                                   u16* __restrict__ wt, u16* __restrict__ w2t,
                                                   u16* __restrict__ bwb,
                                                   const int* __restrict__ flag)
{
  if (flag[0] == 0) prep_body<0>(Wq, Wk, W1, W2, bq, bk, b1, wt, w2t, bwb);
  else              prep_body<1>(Wq, Wk, W1, W2, bq, bk, b1, wt, w2t, bwb);
}

// ---------------- a2t: A2[s][k] (k=2c+hh -> W2[c][2s+hh]; 512+hh -> b2) --
template<int DT>
__device__ __forceinline__ void a2prep_body(const void* W2, const void* b2, u16* a2t)
{
  const int s = blockIdx.x;
  const int c = threadIdx.x;
  a2t[s*544 + 2*c]     = f2bf(ldf<DT>(W2, c*256 + 2*s));
  a2t[s*544 + 2*c + 1] = f2bf(ldf<DT>(W2, c*256 + 2*s + 1));
  if (c < 2)        a2t[s*544 + 512 + c] = f2bf(ldf<DT>(b2, 2*s + c));
  else if (c < 32)  a2t[s*544 + 512 + c] = 0;
}
__global__ __launch_bounds__(256) void a2prep_kernel(const void* __restrict__ W2, const void* __restrict__ b2,
                                                     u16* __restrict__ a2t, const int* __restrict__ flag)
{
  if (flag[0] == 0) a2prep_body<0>(W2, b2, a2t);
  else              a2prep_body<1>(W2, b2, a2t);
}

// ---------------- zero the dump / tile counters --------------------------
__global__ __launch_bounds__(256) void zero_kernel(int* __restrict__ g, int* __restrict__ tcnt)
{
  const int i = blockIdx.x * 256 + threadIdx.x;
  if (i < NQ) g[i] = 0;
  if (i < NT64) tcnt[i] = 0;
}

// ---------------- projections as tiled GEMM (knn_gemm template) ----------
__global__ __launch_bounds__(256) void pgemm_kernel(const u16* __restrict__ xh,
                                                    const u16* __restrict__ wt,
                                                    const u16* __restrict__ bwb,
                                                    u16* __restrict__ SP, u16* __restrict__ DP)
{
  __shared__ u16 cta[128 * 256];   // 64 KB
  const int tid = threadIdx.x, wave = tid >> 6, lane = tid & 63;
  const int l15 = lane & 15, lq = lane >> 4;
  const int qg = wave & 1, cg = wave >> 1;
  const int I0 = blockIdx.x * 128;

  {
    const int rloc = tid >> 5;
    const int cby  = (tid & 31) * 16;
    const int wby  = cby ^ ((rloc & 7) << 4);
    #pragma unroll
    for (int i = 0; i < 16; ++i){
      int grow = I0 + i * 8 + rloc;
      if (grow > NQ - 1) grow = NQ - 1;
      const uint4 v = *(const uint4*)(xh + grow * 256 + (cby >> 1));
      *(uint4*)((char*)cta + (i * 8 + rloc) * 512 + wby) = v;
    }
  }
  __syncthreads();

  const int crb = I0 + cg * 64 + lq * 4;

  #pragma unroll 1
  for (int jp = 0; jp < 2; ++jp){
    const int J0 = (blockIdx.y * 2 + jp) * 128;
    const int q0 = J0 + qg * 64;

    f32x4 acc[4][4];
    #pragma unroll
    for (int cf = 0; cf < 4; ++cf)
      #pragma unroll
      for (int qf = 0; qf < 4; ++qf)
        acc[cf][qf] = (f32x4){0.f, 0.f, 0.f, 0.f};

    #pragma unroll
    for (int ks = 0; ks < 8; ++ks){
      bs8 qv[4];
      #pragma unroll
      for (int qf = 0; qf < 4; ++qf){
        const int wc = q0 + qf * 16 + l15;
        qv[qf] = *(const bs8*)(wt + wc * 256 + ks * 32 + lq * 8);
      }
      bs8 cv[4];
      #pragma unroll
      for (int cf = 0; cf < 4; ++cf){
        const int row = cg * 64 + cf * 16 + l15;
        const int cby = (ks * 64 + lq * 16) ^ ((l15 & 7) << 4);
        cv[cf] = *(const bs8*)((const char*)cta + row * 512 + cby);
      }
      #pragma unroll
      for (int cf = 0; cf < 4; ++cf)
        #pragma unroll
        for (int qf = 0; qf < 4; ++qf)
          acc[cf][qf] = __builtin_amdgcn_mfma_f32_16x16x32_bf16(cv[cf], qv[qf], acc[cf][qf], 0, 0, 0);
    }

    #pragma unroll
    for (int qf = 0; qf < 4; ++qf){
      const int c = q0 + qf * 16 + l15;
      const float bias = (c >= 768) ? bf2f(bwb[c - 768]) : 0.f;
      #pragma unroll
      for (int cf = 0; cf < 4; ++cf){
        #pragma unroll
        for (int q = 0; q < 4; ++q){
          const int node = crb + cf * 16 + q;
          if (node < NQ){
            const u16 v = f2bf(acc[cf][qf][q] + bias);
            if (c < 768) SP[node * 768 + c] = v;
            else         DP[node * 768 + (c - 768)] = v;
          }
        }
      }
    }
  }
}

// ---------------- kNN Gram PASS A: one (I,J) pair per block --------------
__global__ __launch_bounds__(256) void knn_gemm_kernel(
    const u16* __restrict__ xh, const float* __restrict__ n2,
    float* __restrict__ minD)
{
  __shared__ u16 cta[128 * 256];   // 64 KB
  const int tid = threadIdx.x, wave = tid >> 6, lane = tid & 63;
  const int l15 = lane & 15, lq = lane >> 4;
  const int qg = wave & 1, cg = wave >> 1;

  const int p = blockIdx.x;
  int I = 0, s = 0;
  while (s + (79 - I) <= p){ s += 79 - I; ++I; }
  const int J = I + (p - s);
  const int I0 = I * 128, J0 = J * 128;

  {
    const int rloc = tid >> 5;
    const int cby  = (tid & 31) * 16;
    const int wby  = cby ^ ((rloc & 7) << 4);
    #pragma unroll
    for (int i = 0; i < 16; ++i){
      int grow = I0 + i * 8 + rloc;
      if (grow > NQ - 1) grow = NQ - 1;
      const uint4 v = *(const uint4*)(xh + grow * 256 + (cby >> 1));
      *(uint4*)((char*)cta + (i * 8 + rloc) * 512 + wby) = v;
    }
  }
  __syncthreads();

  const int crb = I0 + cg * 64 + lq * 4;
  const int q0 = J0 + qg * 64;

  f32x4 acc[4][4];
  #pragma unroll
  for (int cf = 0; cf < 4; ++cf)
    #pragma unroll
    for (int qf = 0; qf < 4; ++qf)
      acc[cf][qf] = (f32x4){0.f, 0.f, 0.f, 0.f};

  #pragma unroll
  for (int ks = 0; ks < 8; ++ks){
    bs8 qv[4];
    #pragma unroll
    for (int qf = 0; qf < 4; ++qf){
      int qr = q0 + qf * 16 + l15; if (qr > NQ - 1) qr = NQ - 1;
      qv[qf] = *(const bs8*)(xh + qr * 256 + ks * 32 + lq * 8);
    }
    bs8 cv[4];
    #pragma unroll
    for (int cf = 0; cf < 4; ++cf){
      const int row = cg * 64 + cf * 16 + l15;
      const int cby = (ks * 64 + lq * 16) ^ ((l15 & 7) << 4);
      cv[cf] = *(const bs8*)((const char*)cta + row * 512 + cby);
    }
    #pragma unroll
    for (int cf = 0; cf < 4; ++cf)
      #pragma unroll
      for (int qf = 0; qf < 4; ++qf)
        acc[cf][qf] = __builtin_amdgcn_mfma_f32_16x16x32_bf16(cv[cf], qv[qf], acc[cf][qf], 0, 0, 0);
  }

  float n2v[4][4];
  #pragma unroll
  for (int cf = 0; cf < 4; ++cf)
    #pragma unroll
    for (int q = 0; q < 4; ++q){
      int r = crb + cf * 16 + q; if (r > NQ - 1) r = NQ - 1;
      n2v[cf][q] = n2[r];
    }
  float n2c[4];
  #pragma unroll
  for (int qf = 0; qf < 4; ++qf){
    int c = q0 + qf * 16 + l15; if (c > NQ - 1) c = NQ - 1;
    n2c[qf] = n2[c];
  }

  // normal: min over rows -> minD[I-half][col]
  #pragma unroll
  for (int qf = 0; qf < 4; ++qf){
    const int qc = q0 + qf * 16 + l15;
    float m = __builtin_inff();
    #pragma unroll
    for (int cf = 0; cf < 4; ++cf)
      #pragma unroll
      for (int q = 0; q < 4; ++q){
        const int r = crb + cf * 16 + q;
        const float dd = n2v[cf][q] - 2.f * acc[cf][qf][q];
        const bool ok = (r < NQ) && (r != qc);
        m = fminf(m, ok ? dd : __builtin_inff());
      }
    m = fminf(m, __shfl_xor(m, 16));
    m = fminf(m, __shfl_xor(m, 32));
    if (lane < 16){
      const int qs = q0 + qf * 16 + lane;
      if (qs < NQ) minD[(I * 2 + cg) * NQ + qs] = m;
    }
  }
  // transposed (off-diagonal only): min over cols -> minD[J-half][row]
  if (I != J){
    #pragma unroll
    for (int cf = 0; cf < 4; ++cf)
      #pragma unroll
      for (int q = 0; q < 4; ++q){
        float m = __builtin_inff();
        #pragma unroll
        for (int qf = 0; qf < 4; ++qf){
          const int c = q0 + qf * 16 + l15;
          const float v = n2c[qf] - 2.f * acc[cf][qf][q];
          m = fminf(m, (c < NQ) ? v : __builtin_inff());
        }
        m = fminf(m, __shfl_xor(m, 1));
        m = fminf(m, __shfl_xor(m, 2));
        m = fminf(m, __shfl_xor(m, 4));
        m = fminf(m, __shfl_xor(m, 8));
        const int r = crb + cf * 16 + q;
        if (l15 == 0 && r < NQ) minD[(J * 2 + qg) * NQ + r] = m;
      }
  }
}

// ---------------- tau: 16th-smallest tile-min + margin -------------------
__global__ __launch_bounds__(256) void knn_tau_kernel(const float* __restrict__ minD,
                                                      float* __restrict__ tauP)
{
  const int q = blockIdx.x * 256 + threadIdx.x;
  if (q >= NQ) return;
  float ld[16];
  #pragma unroll
  for (int s = 0; s < 16; ++s) ld[s] = __builtin_inff();
  for (int t = 0; t < NT64; ++t){
    float v = minD[t * NQ + q];
    if (v < ld[15]){
      #pragma unroll
      for (int s = 0; s < 16; ++s){
        const bool cmp = v < ld[s];
        const float tv = ld[s];
        ld[s] = cmp ? v : tv;
        v = cmp ? tv : v;
      }
    }
  }
  tauP[q] = ld[15] + MARGIN;
}

// ---------------- build per-tile query lists (wave-per-tile, NO atomics) -
__global__ __launch_bounds__(256) void listbuild_kernel(const float* __restrict__ minD,
                                                        const float* __restrict__ tauP,
                                                        int* __restrict__ tcnt,
                                                        int* __restrict__ qlist)
{
  const int wave = threadIdx.x >> 6, lane = threadIdx.x & 63;
  const int t = blockIdx.x * 4 + wave;
  if (t >= NT64) return;
  const float* row = minD + (size_t)t * NQ;
  int base = 0;
  #pragma unroll 1
  for (int c = 0; c < 157; ++c){
    const int q = c * 64 + lane;
    const bool f = (q < NQ) && (row[q] < tauP[q]);
    const u64 mask = __ballot(f);
    if (f){
      const int off = (int)__popcll(mask & ((1ull << lane) - 1ull));
      qlist[t * NQ + base + off] = q;
    }
    base += (int)__popcll(mask);
  }
  if (lane == 0) tcnt[t] = base;
}

// ---------------- PASS C replacement: tile-centric pruned scan -----------
__global__ __launch_bounds__(256) void knn_scan_kernel(
    const u16* __restrict__ xh, const float* __restrict__ n2,
    const float* __restrict__ tauP, const int* __restrict__ tcnt,
    const int* __restrict__ qlist, int* __restrict__ gcnt,
    u64* __restrict__ candP)
{
  __shared__ u16 cta[64 * 256];   // 32 KB
  const int t = blockIdx.x;
  const int chunk = blockIdx.y;
  const int tid = threadIdx.x, wave = tid >> 6, lane = tid & 63;
  const int l15 = lane & 15, lq = lane >> 4;
  const int I0 = t * 64;

  {
    const int rloc = tid >> 5;
    const int cby  = (tid & 31) * 16;
    const int wby  = cby ^ ((rloc & 7) << 4);
    #pragma unroll
    for (int i = 0; i < 8; ++i){
      int grow = I0 + i * 8 + rloc;
      if (grow > NQ - 1) grow = NQ - 1;
      const uint4 v = *(const uint4*)(xh + grow * 256 + (cby >> 1));
      *(uint4*)((char*)cta + (i * 8 + rloc) * 512 + wby) = v;
    }
  }
  __syncthreads();

  float n2v[4][4];
  #pragma unroll
  for (int cf = 0; cf < 4; ++cf)
    #pragma unroll
    for (int q = 0; q < 4; ++q){
      int r = I0 + cf * 16 + lq * 4 + q; if (r > NQ - 1) r = NQ - 1;
      n2v[cf][q] = n2[r];
    }

  const int cnt = tcnt[t];
  const int ngr = (cnt + 15) >> 4;

  #pragma unroll 1
  for (int gi = chunk * 4 + wave; gi < ngr; gi += 32){
    const int qi = gi * 16 + l15;
    const bool qok = qi < cnt;
    const int qc = qok ? qlist[t * NQ + qi] : 0;

    bs8 qv[8];
    #pragma unroll
    for (int ks = 0; ks < 8; ++ks)
      qv[ks] = *(const bs8*)(xh + qc * 256 + ks * 32 + lq * 8);

    f32x4 acc[4];
    #pragma unroll
    for (int cf = 0; cf < 4; ++cf) acc[cf] = (f32x4){0.f, 0.f, 0.f, 0.f};

    #pragma unroll
    for (int ks = 0; ks < 8; ++ks){
      const int cby = (ks * 64 + lq * 16) ^ ((l15 & 7) << 4);
      #pragma unroll
      for (int cf = 0; cf < 4; ++cf){
        const bs8 cv = *(const bs8*)((const char*)cta + (cf * 16 + l15) * 512 + cby);
        acc[cf] = __builtin_amdgcn_mfma_f32_16x16x32_bf16(cv, qv[ks], acc[cf], 0, 0, 0);
      }
    }

    const float tq = qok ? tauP[qc] : -__builtin_inff();
    #pragma unroll
    for (int cf = 0; cf < 4; ++cf){
      #pragma unroll
      for (int q = 0; q < 4; ++q){
        const int r = I0 + cf * 16 + lq * 4 + q;
        const float dd = n2v[cf][q] - 2.f * acc[cf][q];
        const bool dump = qok && (r < NQ) && (r != qc) && (dd < tq);
        if (dump){
          const int pos = atomicAdd(gcnt + qc, 1);
          if (pos < CAP)
            candP[qc * CAP + pos] =
                (((u64)__float_as_uint(dd + 1024.f)) << 32) | (u32)r;
        }
      }
    }
  }
}

// ---------------- select top-32 of dumped candidates ---------------------
__global__ __launch_bounds__(256) void select32_kernel(const u64* __restrict__ candP,
                                                       const int* __restrict__ gcnt,
                                                       int* __restrict__ cand,
                                                       int* __restrict__ ccnt)
{
  __shared__ u64 sl[4][CAP];
  const int tid = threadIdx.x, wave = tid >> 6, lane = tid & 63;
  const int q = blockIdx.x * 4 + wave;
  int cnt = gcnt[q]; if (cnt > CAP) cnt = CAP;
  const u64* src = candP + (size_t)q * CAP;
  for (int c = lane; c < cnt; c += 64) sl[wave][c] = src[c];
  __syncthreads();
  for (int c = lane; c < cnt; c += 64){
    const u64 me = sl[wave][c];
    int rank = 0;
    for (int o = 0; o < cnt; ++o){
      const u64 ov = sl[wave][o];
      rank += (ov < me || (ov == me && o < c)) ? 1 : 0;
    }
    if (rank < NCAND) cand[q * NCAND + rank] = (int)(me & 0xffffffffu);
  }
  if (lane == 0) ccnt[q] = (cnt < NCAND) ? cnt : NCAND;
}

// ---------------- exact rescore of <=32 candidates -> top-16 -------------
template<int DT>
__device__ __forceinline__ void rescore_body(const void* x, const float* n2,
                                             const int* cand, const int* ccnt, int* knn)
{
  const int tid = threadIdx.x, wave = tid >> 6, lane = tid & 63;
  const int i = blockIdx.x * 4 + wave;
  const int base = i * CD + lane * 4;
  float xi0, xi1, xi2, xi3;
  if (DT == 0){
    const float4 v = *(const float4*)((const float*)x + base);
    xi0 = v.x; xi1 = v.y; xi2 = v.z; xi3 = v.w;
  } else {
    const u32* p = (const u32*)x + (base >> 1);
    const u32 w0 = p[0], w1 = p[1];
    xi0 = bf2f((u16)(w0 & 0xffff)); xi1 = bf2f((u16)(w0 >> 16));
    xi2 = bf2f((u16)(w1 & 0xffff)); xi3 = bf2f((u16)(w1 >> 16));
  }
  const float n2i = n2[i];
  const int cc = ccnt[i];
  const int cown = lane & 31;
  float myd = __builtin_inff(); int myi = NQ + lane;
  for (int c = 0; c < NCAND; ++c){
    const int jr = cand[i * NCAND + c];
    const int j = (c < cc) ? jr : 0;
    const int jb = j * CD + lane * 4;
    float a0, a1, a2, a3;
    if (DT == 0){
      const float4 v = *(const float4*)((const float*)x + jb);
      a0 = v.x; a1 = v.y; a2 = v.z; a3 = v.w;
    } else {
      const u32* p = (const u32*)x + (jb >> 1);
      const u32 w0 = p[0], w1 = p[1];
      a0 = bf2f((u16)(w0 & 0xffff)); a1 = bf2f((u16)(w0 >> 16));
      a2 = bf2f((u16)(w1 & 0xffff)); a3 = bf2f((u16)(w1 >> 16));
    }
    float pdt = xi0*a0 + xi1*a1 + xi2*a2 + xi3*a3;
    #pragma unroll
    for (int m = 1; m < 64; m <<= 1) pdt += __shfl_xor(pdt, m);
    const float d = n2i + n2[j] - 2.f * pdt;
    if (c == cown && c < cc){ myd = d; myi = j; }
  }
  int rank = 0;
  #pragma unroll
  for (int m = 1; m < NCAND; ++m){
    int oc = cown + m; if (oc >= NCAND) oc -= NCAND;
    const float od = __shfl(myd, oc);
    const int   oi = __shfl(myi, oc);
    rank += (od < myd || (od == myd && oi < myi)) ? 1 : 0;
  }
  if (lane < NCAND && rank < KNBR) knn[i * KNBR + rank] = myi;
}
__global__ __launch_bounds__(256) void rescore_kernel(const void* __restrict__ x, const float* __restrict__ n2,
                                                      const int* __restrict__ cand, const int* __restrict__ ccnt,
                                                      int* __restrict__ knn,
                                                      const int* __restrict__ flag)
{
  if (flag[0] == 0) rescore_body<0>(x, n2, cand, ccnt, knn);
  else              rescore_body<1>(x, n2, cand, ccnt, knn);
}

// ---------------- edge2: block-per-node, LDS-staged ----------------------
template<int DT>
__device__ __forceinline__ void edge2_body(const void* x, const u16* SP, const u16* DP,
                                           const int* knn, u16* TB0, u16* TB1,
                                           char* rows, float (*ewb)[4])
{
  const int tid = threadIdx.x;
  const int i = blockIdx.x;

  {
    const int e = tid >> 4, six = tid & 15;
    const int j = knn[i * KNBR + e];
    const int swz = (e & 7) << 4;
    #pragma unroll
    for (int ch = 0; ch < 6; ++ch){
      const uint4 v = *(const uint4*)(SP + j * 768 + ch * 128 + six * 8);
      *(uint4*)(rows + e * 1536 + ((ch * 256 + six * 16) ^ swz)) = v;
    }
    if (tid < 96){
      const uint4 v = *(const uint4*)(DP + i * 768 + tid * 8);
      *(uint4*)(rows + 16 * 1536 + tid * 16) = v;
    }
  }
  __syncthreads();

  {
    const int w = tid >> 6, e = (tid >> 2) & 15, cs = tid & 3;
    const int hh = w >> 1, g = w & 1;
    const int swz = (e & 7) << 4;
    const char* er = rows + e * 1536;
    const char* dr = rows + 16 * 1536;
    float dot = 0.f;
    #pragma unroll
    for (int z = 0; z < 4; ++z){
      const int qoff = hh * 256 + cs * 64 + z * 16;
      const int koff = 512 + g * 256 + cs * 64 + z * 16;
      const bs8 sq = *(const bs8*)(er + (qoff ^ swz));
      const bs8 dq = *(const bs8*)(dr + qoff);
      const bs8 sk = *(const bs8*)(er + (koff ^ swz));
      const bs8 dk = *(const bs8*)(dr + koff);
      #pragma unroll
      for (int m = 0; m < 8; ++m){
        const float Q = bf2f((u16)sq[m]) + bf2f((u16)dq[m]);
        const float K = bf2f((u16)sk[m]) + bf2f((u16)dk[m]);
        dot += Q * K;
      }
    }
    dot += __shfl_xor(dot, 1);
    dot += __shfl_xor(dot, 2);
    if (cs == 0) ewb[e][w] = dot * 0.0625f;
  }
  __syncthreads();

  if (tid < 4){
    float S = 0.f;
    #pragma unroll
    for (int e = 0; e < 16; ++e) S += ewb[e][tid];
    const int hh = tid >> 1, g = tid & 1;
    (g ? TB1 : TB0)[i * 544 + 512 + hh] = f2bf(S);
  } else if (tid < 34){
    TB0[i * 544 + 510 + tid] = 0;
    TB1[i * 544 + 510 + tid] = 0;
  }

  {
    const int c = tid;
    const float A1c = bf2f(*(const u16*)(rows + 16 * 1536 + 1024 + 2 * c));
    const float xi = ldf<DT>(x, i * 256 + c);
    float T0 = 0.f, T1 = 0.f, T2 = 0.f, T3 = 0.f;
    #pragma unroll
    for (int e = 0; e < 16; ++e){
      const float4 e4 = *(const float4*)&ewb[e][0];
      const float B1 = bf2f(*(const u16*)(rows + e * 1536 + ((1024 + 2 * c) ^ ((e & 7) << 4))));
      const float h = fmaxf(A1c + B1, 0.f) + xi;
      T0 += h * e4.x; T1 += h * e4.y; T2 += h * e4.z; T3 += h * e4.w;
    }
    *(u32*)(TB0 + i * 544 + 2 * c) = (u32)f2bf(T0) | ((u32)f2bf(T2) << 16);
    *(u32*)(TB1 + i * 544 + 2 * c) = (u32)f2bf(T1) | ((u32)f2bf(T3) << 16);
  }
}
__global__ __launch_bounds__(256) void edge2_kernel(
    const void* __restrict__ x, const u16* __restrict__ SP, const u16* __restrict__ DP,
    const int* __restrict__ knn, u16* __restrict__ TB0, u16* __restrict__ TB1,
    const int* __restrict__ flag)
{
  __shared__ char rows[17 * 1536];
  __shared__ float ewb[16][4];
  if (flag[0] == 0) edge2_body<0>(x, SP, DP, knn, TB0, TB1, rows, ewb);
  else              edge2_body<1>(x, SP, DP, knn, TB0, TB1, rows, ewb);
}

// ---------------- fgemm: OUT_g = TBg @ A2^T (incl. bias-S, /16) ----------
template<int DT>
__device__ __forceinline__ void fgemm_body(const u16* TB0, const u16* TB1,
                                           const u16* a2t, void* out)
{
  const int tid = threadIdx.x, wave = tid >> 6, lane = tid & 63;
  const int l15 = lane & 15, lq = lane >> 4;
  const int I0 = blockIdx.x * 64;
  const int s0 = blockIdx.y * 64;
  const int g = wave & 1, nh = wave >> 1;
  const u16* TB = g ? TB1 : TB0;
  const int nodeb = I0 + nh * 32;

  f32x4 acc[2][4];
  #pragma unroll
  for (int cf = 0; cf < 2; ++cf)
    #pragma unroll
    for (int qf = 0; qf < 4; ++qf) acc[cf][qf] = (f32x4){0.f, 0.f, 0.f, 0.f};

  #pragma unroll
  for (int ks = 0; ks < 17; ++ks){
    bs8 av[2], bv[4];
    #pragma unroll
    for (int cf = 0; cf < 2; ++cf){
      int nr = nodeb + cf * 16 + l15; if (nr > NQ - 1) nr = NQ - 1;
      av[cf] = *(const bs8*)(TB + nr * 544 + ks * 32 + lq * 8);
    }
    #pragma unroll
    for (int qf = 0; qf < 4; ++qf)
      bv[qf] = *(const bs8*)(a2t + (s0 + qf * 16 + l15) * 544 + ks * 32 + lq * 8);
    #pragma unroll
    for (int cf = 0; cf < 2; ++cf)
      #pragma unroll
      for (int qf = 0; qf < 4; ++qf)
        acc[cf][qf] = __builtin_amdgcn_mfma_f32_16x16x32_bf16(av[cf], bv[qf], acc[cf][qf], 0, 0, 0);
  }

  #pragma unroll
  for (int cf = 0; cf < 2; ++cf)
    #pragma unroll
    for (int qf = 0; qf < 4; ++qf){
      const int scol = s0 + qf * 16 + l15;
      #pragma unroll
      for (int q = 0; q < 4; ++q){
        const int node = nodeb + cf * 16 + lq * 4 + q;
        if (node < NQ){
          const float val = acc[cf][qf][q] * 0.0625f;
          if (DT == 0) ((float*)out)[node * 256 + 2 * scol + g] = val;
          else         ((u16*)out)[node * 256 + 2 * scol + g] = f2bf(val);
        }
      }
    }
}
__global__ __launch_bounds__(256) void fgemm_kernel(const u16* __restrict__ TB0, const u16* __restrict__ TB1,
                                                    const u16* __restrict__ a2t, void* __restrict__ out,
                                                    const int* __restrict__ flag)
{
  if (flag[0] == 0) fgemm_body<0>(TB0, TB1, a2t, out);
  else              fgemm_body<1>(TB0, TB1, a2t, out);
}

extern "C" void kernel_launch(void* const* d_in, const int* in_sizes, int n_in,
                              void* d_out, int out_size, void* d_ws, size_t ws_size,
                              hipStream_t stream)
{
  const void* x  = d_in[0];
  const void* W1 = d_in[1];
  const void* b1 = d_in[2];
  const void* W2 = d_in[3];
  const void* b2 = d_in[4];
  const void* Wq = d_in[5];
  const void* bq = d_in[6];
  const void* Wk = d_in[7];
  const void* bk = d_in[8];

  char* ws = (char*)d_ws;
  int*   flag  = (int*)ws;                    // 64
  u16*   xh    = (u16*)(ws + 64);             // 5,120,000
  u16*   wt    = (u16*)(ws + 5120064);        // 786,432
  u16*   a2t   = (u16*)(ws + 5906496);        // 139,264
  u16*   w2t   = (u16*)(ws + 6045760);        // 131,072 (written by prep job 6; unused)
  u16*   bwb   = (u16*)(ws + 6176832);        // 1,536
  float* n2    = (float*)(ws + 6178368);      // 40,000
  float* tauP  = (float*)(ws + 6218368);      // 40,000
  int*   gcnt  = (int*)(ws + 6258368);        // 40,000
  int*   ccnt  = (int*)(ws + 6298368);        // 40,000
  int*   knn   = (int*)(ws + 6338368);        // 640,000
  int*   cand  = (int*)(ws + 6978368);        // 1,280,000
  float* minD  = (float*)(ws + 8258368);      // 6,320,000 (window with candP)
  u64*   candP = (u64*)(ws + 8258368);        // 10,240,000
  u16*   SP    = (u16*)(ws + 18498368);       // 15,360,000
  u16*   DP    = (u16*)(ws + 33858368);       // 15,360,000
  u16*   TB0   = (u16*)(ws + 6978368);        // 10,880,000 (aliases cand+candP, dead by then)
  int*   tcnt  = (int*)(ws + 49218368);       // 640 (TB1 region; dead before edge2)
  int*   qlist = (int*)(ws + 49219008);       // 158*10000*4 = 6,320,000
  u16*   TB1   = (u16*)(ws + 49218368);       // 10,880,000 (edge2 phase only)
  // total (big path): 60,098,368 bytes
  (void)ws_size;

  detect_kernel<<<1, 256, 0, stream>>>((const u32*)x, flag);

  cvtn2_kernel<<<2500, 256, 0, stream>>>(x, xh, n2, flag);
  prep_kernel<<<8, 256, 0, stream>>>(Wq, Wk, W1, W2, bq, bk, b1, wt, w2t, bwb, flag);
  a2prep_kernel<<<128, 256, 0, stream>>>(W2, b2, a2t, flag);
  zero_kernel<<<40, 256, 0, stream>>>(gcnt, tcnt);

  pgemm_kernel<<<dim3(79, 6), 256, 0, stream>>>(xh, wt, bwb, SP, DP);

  knn_gemm_kernel<<<NPAIR, 256, 0, stream>>>(xh, n2, minD);
  knn_tau_kernel<<<40, 256, 0, stream>>>(minD, tauP);
  listbuild_kernel<<<40, 256, 0, stream>>>(minD, tauP, tcnt, qlist);
  knn_scan_kernel<<<dim3(NT64, 8), 256, 0, stream>>>(xh, n2, tauP, tcnt, qlist, gcnt, candP);
  select32_kernel<<<2500, 256, 0, stream>>>(candP, gcnt, cand, ccnt);

  rescore_kernel<<<2500, 256, 0, stream>>>(x, n2, cand, ccnt, knn, flag);

  edge2_kernel<<<10000, 256, 0, stream>>>(x, SP, DP, knn, TB0, TB1, flag);
  fgemm_kernel<<<dim3(157, 2), 256, 0, stream>>>(TB0, TB1, a2t, d_out, flag);
}

// Round 20
// 417.022 us; speedup vs baseline: 1.1478x; 1.0401x over previous
//
#include <hip/hip_runtime.h>

#define NQ    10000
#define CD    256
#define KNBR  16
#define NCAND 32
#define CAP   128
#define NT64  158        // 79 tiles x 2 half-tiles of 64 cand rows
#define NPAIR 3160       // 79*80/2 upper-triangle tile pairs
#define NPG   474        // pgemm blocks (79 x 6)
#define MARGIN 2.0f

typedef short bs8 __attribute__((ext_vector_type(8)));
typedef float f32x4 __attribute__((ext_vector_type(4)));
typedef unsigned short u16;
typedef unsigned int u32;
typedef unsigned long long u64;
typedef unsigned short us4 __attribute__((ext_vector_type(4)));

__device__ __forceinline__ float bf2f(u16 u){
  union { u32 i; float f; } c; c.i = ((u32)u) << 16; return c.f;
}
__device__ __forceinline__ u16 f2bf(float f){
  union { float f; u32 i; } c; c.f = f;
  u32 u = c.i;
  u += 0x7fffu + ((u >> 16) & 1u);   // RTNE
  return (u16)(u >> 16);
}
template<int DT>
__device__ __forceinline__ float ldf(const void* p, int i){
  if (DT) return bf2f(((const u16*)p)[i]);
  return ((const float*)p)[i];
}

// ---------------- dtype detect: flag=0 f32, flag=1 bf16 ------------------
__global__ __launch_bounds__(256) void detect_kernel(const u32* __restrict__ xw, int* __restrict__ flag)
{
  __shared__ int cnt;
  if (threadIdx.x == 0) cnt = 0;
  __syncthreads();
  const u32 w = xw[threadIdx.x];
  const int e = (int)((w >> 7) & 0xff);
  if (e >= 120 && e <= 131) atomicAdd(&cnt, 1);
  __syncthreads();
  if (threadIdx.x == 0) flag[0] = (cnt >= 128) ? 1 : 0;
}

// ---------------- x -> bf16 convert + row norms (fused, runtime dt) ------
__global__ __launch_bounds__(256) void cvtn2_kernel(const void* __restrict__ xin, u16* __restrict__ xh,
                                                    float* __restrict__ n2, const int* __restrict__ flag)
{
  const int dt = flag[0];
  const int tid = threadIdx.x, lane = tid & 63;
  const int idx = (blockIdx.x * 256 + tid) * 4;
  float a, b, c, d;
  us4 r;
  if (dt == 0){
    const float4 v = *(const float4*)((const float*)xin + idx);
    a = v.x; b = v.y; c = v.z; d = v.w;
    r[0] = f2bf(a); r[1] = f2bf(b); r[2] = f2bf(c); r[3] = f2bf(d);
  } else {
    r = *(const us4*)((const u16*)xin + idx);
    a = bf2f((u16)r[0]); b = bf2f((u16)r[1]); c = bf2f((u16)r[2]); d = bf2f((u16)r[3]);
  }
  *(us4*)(xh + idx) = r;
  float s = a*a + b*b + c*c + d*d;
  #pragma unroll
  for (int m = 1; m < 64; m <<= 1) s += __shfl_xor(s, m);
  if (lane == 0) n2[idx >> 8] = s;
}

// ---------------- prep: weight transposes + bias bf16 copies -------------
template<int DT>
__device__ __forceinline__ void prep_body(const void* Wq, const void* Wk,
                                          const void* W1, const void* W2,
                                          const void* bq, const void* bk, const void* b1,
                                          u16* wt, u16* w2t, u16* bwb)
{
  const int job = blockIdx.x, n = threadIdx.x;
  if (job == 7){
    bwb[n]       = f2bf(ldf<DT>(bq, n));
    bwb[256 + n] = f2bf(ldf<DT>(bk, n));
    bwb[512 + n] = f2bf(ldf<DT>(b1, n));
    return;
  }
  const void* src; int soff; u16* dst;
  switch (job){
    case 0: src = Wq; soff = 0;     dst = wt;          break;
    case 1: src = Wk; soff = 0;     dst = wt + 65536;  break;
    case 2: src = W1; soff = 65536; dst = wt + 131072; break;
    case 3: src = Wq; soff = 65536; dst = wt + 196608; break;
    case 4: src = Wk; soff = 65536; dst = wt + 262144; break;
    case 5: src = W1; soff = 0;     dst = wt + 327680; break;
    default: src = W2; soff = 0;    dst = w2t;         break;
  }
  for (int c = 0; c < 256; ++c)
    dst[n*256 + c] = f2bf(ldf<DT>(src, soff + c*256 + n));
}
__global__ __launch_bounds__(256) void prep_kernel(const void* __restrict__ Wq, const void* __restrict__ Wk,
                                                   const void* __restrict__ W1, const void* __restrict__ W2,
                                                   const void* __restrict__ bq, const void* __restrict__ bk,
                                                   const void* __restrict__ b1,
                                                   u16* __restrict__ wt, u16* __restrict__ w2t,
                                                   u16* __restrict__ bwb,
                                                   const int* __restrict__ flag)
{
  if (flag[0] == 0) prep_body<0>(Wq, Wk, W1, W2, bq, bk, b1, wt, w2t, bwb);
  else              prep_body<1>(Wq, Wk, W1, W2, bq, bk, b1, wt, w2t, bwb);
}

// ---------------- a2t: A2[s][k] (k=2c+hh -> W2[c][2s+hh]; 512+hh -> b2) --
template<int DT>
__device__ __forceinline__ void a2prep_body(const void* W2, const void* b2, u16* a2t)
{
  const int s = blockIdx.x;
  const int c = threadIdx.x;
  a2t[s*544 + 2*c]     = f2bf(ldf<DT>(W2, c*256 + 2*s));
  a2t[s*544 + 2*c + 1] = f2bf(ldf<DT>(W2, c*256 + 2*s + 1));
  if (c < 2)        a2t[s*544 + 512 + c] = f2bf(ldf<DT>(b2, 2*s + c));
  else if (c < 32)  a2t[s*544 + 512 + c] = 0;
}
__global__ __launch_bounds__(256) void a2prep_kernel(const void* __restrict__ W2, const void* __restrict__ b2,
                                                     u16* __restrict__ a2t, const int* __restrict__ flag)
{
  if (flag[0] == 0) a2prep_body<0>(W2, b2, a2t);
  else              a2prep_body<1>(W2, b2, a2t);
}

// ---------------- zero the dump / tile counters --------------------------
__global__ __launch_bounds__(256) void zero_kernel(int* __restrict__ g, int* __restrict__ tcnt)
{
  const int i = blockIdx.x * 256 + threadIdx.x;
  if (i < NQ) g[i] = 0;
  if (i < NT64) tcnt[i] = 0;
}

// ---------------- pgemm body (projections as tiled GEMM) -----------------
__device__ __forceinline__ void pgemm_dev(u16* cta,
                                          const u16* __restrict__ xh,
                                          const u16* __restrict__ wt,
                                          const u16* __restrict__ bwb,
                                          u16* __restrict__ SP, u16* __restrict__ DP,
                                          int bx, int by)
{
  const int tid = threadIdx.x, wave = tid >> 6, lane = tid & 63;
  const int l15 = lane & 15, lq = lane >> 4;
  const int qg = wave & 1, cg = wave >> 1;
  const int I0 = bx * 128;

  {
    const int rloc = tid >> 5;
    const int cby  = (tid & 31) * 16;
    const int wby  = cby ^ ((rloc & 7) << 4);
    #pragma unroll
    for (int i = 0; i < 16; ++i){
      int grow = I0 + i * 8 + rloc;
      if (grow > NQ - 1) grow = NQ - 1;
      const uint4 v = *(const uint4*)(xh + grow * 256 + (cby >> 1));
      *(uint4*)((char*)cta + (i * 8 + rloc) * 512 + wby) = v;
    }
  }
  __syncthreads();

  const int crb = I0 + cg * 64 + lq * 4;

  #pragma unroll 1
  for (int jp = 0; jp < 2; ++jp){
    const int J0 = (by * 2 + jp) * 128;
    const int q0 = J0 + qg * 64;

    f32x4 acc[4][4];
    #pragma unroll
    for (int cf = 0; cf < 4; ++cf)
      #pragma unroll
      for (int qf = 0; qf < 4; ++qf)
        acc[cf][qf] = (f32x4){0.f, 0.f, 0.f, 0.f};

    #pragma unroll
    for (int ks = 0; ks < 8; ++ks){
      bs8 qv[4];
      #pragma unroll
      for (int qf = 0; qf < 4; ++qf){
        const int wc = q0 + qf * 16 + l15;
        qv[qf] = *(const bs8*)(wt + wc * 256 + ks * 32 + lq * 8);
      }
      bs8 cv[4];
      #pragma unroll
      for (int cf = 0; cf < 4; ++cf){
        const int row = cg * 64 + cf * 16 + l15;
        const int cby = (ks * 64 + lq * 16) ^ ((l15 & 7) << 4);
        cv[cf] = *(const bs8*)((const char*)cta + row * 512 + cby);
      }
      #pragma unroll
      for (int cf = 0; cf < 4; ++cf)
        #pragma unroll
        for (int qf = 0; qf < 4; ++qf)
          acc[cf][qf] = __builtin_amdgcn_mfma_f32_16x16x32_bf16(cv[cf], qv[qf], acc[cf][qf], 0, 0, 0);
    }

    #pragma unroll
    for (int qf = 0; qf < 4; ++qf){
      const int c = q0 + qf * 16 + l15;
      const float bias = (c >= 768) ? bf2f(bwb[c - 768]) : 0.f;
      #pragma unroll
      for (int cf = 0; cf < 4; ++cf){
        #pragma unroll
        for (int q = 0; q < 4; ++q){
          const int node = crb + cf * 16 + q;
          if (node < NQ){
            const u16 v = f2bf(acc[cf][qf][q] + bias);
            if (c < 768) SP[node * 768 + c] = v;
            else         DP[node * 768 + (c - 768)] = v;
          }
        }
      }
    }
    __syncthreads();
  }
}

// ---------------- knn_gemm body (one (I,J) pair) -------------------------
__device__ __forceinline__ void knngemm_dev(u16* cta,
                                            const u16* __restrict__ xh,
                                            const float* __restrict__ n2,
                                            float* __restrict__ minD, int p)
{
  const int tid = threadIdx.x, wave = tid >> 6, lane = tid & 63;
  const int l15 = lane & 15, lq = lane >> 4;
  const int qg = wave & 1, cg = wave >> 1;

  int I = 0, s = 0;
  while (s + (79 - I) <= p){ s += 79 - I; ++I; }
  const int J = I + (p - s);
  const int I0 = I * 128, J0 = J * 128;

  {
    const int rloc = tid >> 5;
    const int cby  = (tid & 31) * 16;
    const int wby  = cby ^ ((rloc & 7) << 4);
    #pragma unroll
    for (int i = 0; i < 16; ++i){
      int grow = I0 + i * 8 + rloc;
      if (grow > NQ - 1) grow = NQ - 1;
      const uint4 v = *(const uint4*)(xh + grow * 256 + (cby >> 1));
      *(uint4*)((char*)cta + (i * 8 + rloc) * 512 + wby) = v;
    }
  }
  __syncthreads();

  const int crb = I0 + cg * 64 + lq * 4;
  const int q0 = J0 + qg * 64;

  f32x4 acc[4][4];
  #pragma unroll
  for (int cf = 0; cf < 4; ++cf)
    #pragma unroll
    for (int qf = 0; qf < 4; ++qf)
      acc[cf][qf] = (f32x4){0.f, 0.f, 0.f, 0.f};

  #pragma unroll
  for (int ks = 0; ks < 8; ++ks){
    bs8 qv[4];
    #pragma unroll
    for (int qf = 0; qf < 4; ++qf){
      int qr = q0 + qf * 16 + l15; if (qr > NQ - 1) qr = NQ - 1;
      qv[qf] = *(const bs8*)(xh + qr * 256 + ks * 32 + lq * 8);
    }
    bs8 cv[4];
    #pragma unroll
    for (int cf = 0; cf < 4; ++cf){
      const int row = cg * 64 + cf * 16 + l15;
      const int cby = (ks * 64 + lq * 16) ^ ((l15 & 7) << 4);
      cv[cf] = *(const bs8*)((const char*)cta + row * 512 + cby);
    }
    #pragma unroll
    for (int cf = 0; cf < 4; ++cf)
      #pragma unroll
      for (int qf = 0; qf < 4; ++qf)
        acc[cf][qf] = __builtin_amdgcn_mfma_f32_16x16x32_bf16(cv[cf], qv[qf], acc[cf][qf], 0, 0, 0);
  }

  float n2v[4][4];
  #pragma unroll
  for (int cf = 0; cf < 4; ++cf)
    #pragma unroll
    for (int q = 0; q < 4; ++q){
      int r = crb + cf * 16 + q; if (r > NQ - 1) r = NQ - 1;
      n2v[cf][q] = n2[r];
    }
  float n2c[4];
  #pragma unroll
  for (int qf = 0; qf < 4; ++qf){
    int c = q0 + qf * 16 + l15; if (c > NQ - 1) c = NQ - 1;
    n2c[qf] = n2[c];
  }

  // normal: min over rows -> minD[I-half][col]
  #pragma unroll
  for (int qf = 0; qf < 4; ++qf){
    const int qc = q0 + qf * 16 + l15;
    float m = __builtin_inff();
    #pragma unroll
    for (int cf = 0; cf < 4; ++cf)
      #pragma unroll
      for (int q = 0; q < 4; ++q){
        const int r = crb + cf * 16 + q;
        const float dd = n2v[cf][q] - 2.f * acc[cf][qf][q];
        const bool ok = (r < NQ) && (r != qc);
        m = fminf(m, ok ? dd : __builtin_inff());
      }
    m = fminf(m, __shfl_xor(m, 16));
    m = fminf(m, __shfl_xor(m, 32));
    if (lane < 16){
      const int qs = q0 + qf * 16 + lane;
      if (qs < NQ) minD[(I * 2 + cg) * NQ + qs] = m;
    }
  }
  // transposed (off-diagonal only): min over cols -> minD[J-half][row]
  if (I != J){
    #pragma unroll
    for (int cf = 0; cf < 4; ++cf)
      #pragma unroll
      for (int q = 0; q < 4; ++q){
        float m = __builtin_inff();
        #pragma unroll
        for (int qf = 0; qf < 4; ++qf){
          const int c = q0 + qf * 16 + l15;
          const float v = n2c[qf] - 2.f * acc[cf][qf][q];
          m = fminf(m, (c < NQ) ? v : __builtin_inff());
        }
        m = fminf(m, __shfl_xor(m, 1));
        m = fminf(m, __shfl_xor(m, 2));
        m = fminf(m, __shfl_xor(m, 4));
        m = fminf(m, __shfl_xor(m, 8));
        const int r = crb + cf * 16 + q;
        if (l15 == 0 && r < NQ) minD[(J * 2 + qg) * NQ + r] = m;
      }
  }
}

// ---------------- FUSED: pgemm (474 blocks) + knn_gemm (3160 pairs) ------
// Independent outputs (SP/DP vs minD); one dispatch lets knn blocks backfill
// pgemm's ramp/tail. pgemm blocks first so SP/DP finish early.
__global__ __launch_bounds__(256) void gemm_fused_kernel(
    const u16* __restrict__ xh, const u16* __restrict__ wt,
    const u16* __restrict__ bwb, u16* __restrict__ SP, u16* __restrict__ DP,
    const float* __restrict__ n2, float* __restrict__ minD)
{
  __shared__ u16 cta[128 * 256];   // 64 KB, shared by both bodies
  const int b = blockIdx.x;
  if (b < NPG) pgemm_dev(cta, xh, wt, bwb, SP, DP, b % 79, b / 79);
  else         knngemm_dev(cta, xh, n2, minD, b - NPG);
}

// ---------------- tau: 16th-smallest tile-min + margin -------------------
__global__ __launch_bounds__(256) void knn_tau_kernel(const float* __restrict__ minD,
                                                      float* __restrict__ tauP)
{
  const int q = blockIdx.x * 256 + threadIdx.x;
  if (q >= NQ) return;
  float ld[16];
  #pragma unroll
  for (int s = 0; s < 16; ++s) ld[s] = __builtin_inff();
  for (int t = 0; t < NT64; ++t){
    float v = minD[t * NQ + q];
    if (v < ld[15]){
      #pragma unroll
      for (int s = 0; s < 16; ++s){
        const bool cmp = v < ld[s];
        const float tv = ld[s];
        ld[s] = cmp ? v : tv;
        v = cmp ? tv : v;
      }
    }
  }
  tauP[q] = ld[15] + MARGIN;
}

// ---------------- build per-tile query lists (wave-per-tile, NO atomics) -
__global__ __launch_bounds__(256) void listbuild_kernel(const float* __restrict__ minD,
                                                        const float* __restrict__ tauP,
                                                        int* __restrict__ tcnt,
                                                        int* __restrict__ qlist)
{
  const int wave = threadIdx.x >> 6, lane = threadIdx.x & 63;
  const int t = blockIdx.x * 4 + wave;
  if (t >= NT64) return;
  const float* row = minD + (size_t)t * NQ;
  int base = 0;
  #pragma unroll 1
  for (int c = 0; c < 157; ++c){
    const int q = c * 64 + lane;
    const bool f = (q < NQ) && (row[q] < tauP[q]);
    const u64 mask = __ballot(f);
    if (f){
      const int off = (int)__popcll(mask & ((1ull << lane) - 1ull));
      qlist[t * NQ + base + off] = q;
    }
    base += (int)__popcll(mask);
  }
  if (lane == 0) tcnt[t] = base;
}

// ---------------- PASS C replacement: tile-centric pruned scan -----------
__global__ __launch_bounds__(256) void knn_scan_kernel(
    const u16* __restrict__ xh, const float* __restrict__ n2,
    const float* __restrict__ tauP, const int* __restrict__ tcnt,
    const int* __restrict__ qlist, int* __restrict__ gcnt,
    u64* __restrict__ candP)
{
  __shared__ u16 cta[64 * 256];   // 32 KB
  const int t = blockIdx.x;
  const int chunk = blockIdx.y;
  const int tid = threadIdx.x, wave = tid >> 6, lane = tid & 63;
  const int l15 = lane & 15, lq = lane >> 4;
  const int I0 = t * 64;

  {
    const int rloc = tid >> 5;
    const int cby  = (tid & 31) * 16;
    const int wby  = cby ^ ((rloc & 7) << 4);
    #pragma unroll
    for (int i = 0; i < 8; ++i){
      int grow = I0 + i * 8 + rloc;
      if (grow > NQ - 1) grow = NQ - 1;
      const uint4 v = *(const uint4*)(xh + grow * 256 + (cby >> 1));
      *(uint4*)((char*)cta + (i * 8 + rloc) * 512 + wby) = v;
    }
  }
  __syncthreads();

  float n2v[4][4];
  #pragma unroll
  for (int cf = 0; cf < 4; ++cf)
    #pragma unroll
    for (int q = 0; q < 4; ++q){
      int r = I0 + cf * 16 + lq * 4 + q; if (r > NQ - 1) r = NQ - 1;
      n2v[cf][q] = n2[r];
    }

  const int cnt = tcnt[t];
  const int ngr = (cnt + 15) >> 4;

  #pragma unroll 1
  for (int gi = chunk * 4 + wave; gi < ngr; gi += 32){
    const int qi = gi * 16 + l15;
    const bool qok = qi < cnt;
    const int qc = qok ? qlist[t * NQ + qi] : 0;

    bs8 qv[8];
    #pragma unroll
    for (int ks = 0; ks < 8; ++ks)
      qv[ks] = *(const bs8*)(xh + qc * 256 + ks * 32 + lq * 8);

    f32x4 acc[4];
    #pragma unroll
    for (int cf = 0; cf < 4; ++cf) acc[cf] = (f32x4){0.f, 0.f, 0.f, 0.f};

    #pragma unroll
    for (int ks = 0; ks < 8; ++ks){
      const int cby = (ks * 64 + lq * 16) ^ ((l15 & 7) << 4);
      #pragma unroll
      for (int cf = 0; cf < 4; ++cf){
        const bs8 cv = *(const bs8*)((const char*)cta + (cf * 16 + l15) * 512 + cby);
        acc[cf] = __builtin_amdgcn_mfma_f32_16x16x32_bf16(cv, qv[ks], acc[cf], 0, 0, 0);
      }
    }

    const float tq = qok ? tauP[qc] : -__builtin_inff();
    #pragma unroll
    for (int cf = 0; cf < 4; ++cf){
      #pragma unroll
      for (int q = 0; q < 4; ++q){
        const int r = I0 + cf * 16 + lq * 4 + q;
        const float dd = n2v[cf][q] - 2.f * acc[cf][q];
        const bool dump = qok && (r < NQ) && (r != qc) && (dd < tq);
        if (dump){
          const int pos = atomicAdd(gcnt + qc, 1);
          if (pos < CAP)
            candP[qc * CAP + pos] =
                (((u64)__float_as_uint(dd + 1024.f)) << 32) | (u32)r;
        }
      }
    }
  }
}

// ---------------- select top-32 of dumped candidates ---------------------
__global__ __launch_bounds__(256) void select32_kernel(const u64* __restrict__ candP,
                                                       const int* __restrict__ gcnt,
                                                       int* __restrict__ cand,
                                                       int* __restrict__ ccnt)
{
  __shared__ u64 sl[4][CAP];
  const int tid = threadIdx.x, wave = tid >> 6, lane = tid & 63;
  const int q = blockIdx.x * 4 + wave;
  int cnt = gcnt[q]; if (cnt > CAP) cnt = CAP;
  const u64* src = candP + (size_t)q * CAP;
  for (int c = lane; c < cnt; c += 64) sl[wave][c] = src[c];
  __syncthreads();
  for (int c = lane; c < cnt; c += 64){
    const u64 me = sl[wave][c];
    int rank = 0;
    for (int o = 0; o < cnt; ++o){
      const u64 ov = sl[wave][o];
      rank += (ov < me || (ov == me && o < c)) ? 1 : 0;
    }
    if (rank < NCAND) cand[q * NCAND + rank] = (int)(me & 0xffffffffu);
  }
  if (lane == 0) ccnt[q] = (cnt < NCAND) ? cnt : NCAND;
}

// ---------------- exact rescore of <=32 candidates -> top-16 -------------
template<int DT>
__device__ __forceinline__ void rescore_body(const void* x, const float* n2,
                                             const int* cand, const int* ccnt, int* knn)
{
  const int tid = threadIdx.x, wave = tid >> 6, lane = tid & 63;
  const int i = blockIdx.x * 4 + wave;
  const int base = i * CD + lane * 4;
  float xi0, xi1, xi2, xi3;
  if (DT == 0){
    const float4 v = *(const float4*)((const float*)x + base);
    xi0 = v.x; xi1 = v.y; xi2 = v.z; xi3 = v.w;
  } else {
    const u32* p = (const u32*)x + (base >> 1);
    const u32 w0 = p[0], w1 = p[1];
    xi0 = bf2f((u16)(w0 & 0xffff)); xi1 = bf2f((u16)(w0 >> 16));
    xi2 = bf2f((u16)(w1 & 0xffff)); xi3 = bf2f((u16)(w1 >> 16));
  }
  const float n2i = n2[i];
  const int cc = ccnt[i];
  const int cown = lane & 31;
  float myd = __builtin_inff(); int myi = NQ + lane;
  for (int c = 0; c < NCAND; ++c){
    const int jr = cand[i * NCAND + c];
    const int j = (c < cc) ? jr : 0;
    const int jb = j * CD + lane * 4;
    float a0, a1, a2, a3;
    if (DT == 0){
      const float4 v = *(const float4*)((const float*)x + jb);
      a0 = v.x; a1 = v.y; a2 = v.z; a3 = v.w;
    } else {
      const u32* p = (const u32*)x + (jb >> 1);
      const u32 w0 = p[0], w1 = p[1];
      a0 = bf2f((u16)(w0 & 0xffff)); a1 = bf2f((u16)(w0 >> 16));
      a2 = bf2f((u16)(w1 & 0xffff)); a3 = bf2f((u16)(w1 >> 16));
    }
    float pdt = xi0*a0 + xi1*a1 + xi2*a2 + xi3*a3;
    #pragma unroll
    for (int m = 1; m < 64; m <<= 1) pdt += __shfl_xor(pdt, m);
    const float d = n2i + n2[j] - 2.f * pdt;
    if (c == cown && c < cc){ myd = d; myi = j; }
  }
  int rank = 0;
  #pragma unroll
  for (int m = 1; m < NCAND; ++m){
    int oc = cown + m; if (oc >= NCAND) oc -= NCAND;
    const float od = __shfl(myd, oc);
    const int   oi = __shfl(myi, oc);
    rank += (od < myd || (od == myd && oi < myi)) ? 1 : 0;
  }
  if (lane < NCAND && rank < KNBR) knn[i * KNBR + rank] = myi;
}
__global__ __launch_bounds__(256) void rescore_kernel(const void* __restrict__ x, const float* __restrict__ n2,
                                                      const int* __restrict__ cand, const int* __restrict__ ccnt,
                                                      int* __restrict__ knn,
                                                      const int* __restrict__ flag)
{
  if (flag[0] == 0) rescore_body<0>(x, n2, cand, ccnt, knn);
  else              rescore_body<1>(x, n2, cand, ccnt, knn);
}

// ---------------- edge2: block-per-node, LDS-staged ----------------------
template<int DT>
__device__ __forceinline__ void edge2_body(const void* x, const u16* SP, const u16* DP,
                                           const int* knn, u16* TB0, u16* TB1,
                                           char* rows, float (*ewb)[4])
{
  const int tid = threadIdx.x;
  const int i = blockIdx.x;

  {
    const int e = tid >> 4, six = tid & 15;
    const int j = knn[i * KNBR + e];
    const int swz = (e & 7) << 4;
    #pragma unroll
    for (int ch = 0; ch < 6; ++ch){
      const uint4 v = *(const uint4*)(SP + j * 768 + ch * 128 + six * 8);
      *(uint4*)(rows + e * 1536 + ((ch * 256 + six * 16) ^ swz)) = v;
    }
    if (tid < 96){
      const uint4 v = *(const uint4*)(DP + i * 768 + tid * 8);
      *(uint4*)(rows + 16 * 1536 + tid * 16) = v;
    }
  }
  __syncthreads();

  {
    const int w = tid >> 6, e = (tid >> 2) & 15, cs = tid & 3;
    const int hh = w >> 1, g = w & 1;
    const int swz = (e & 7) << 4;
    const char* er = rows + e * 1536;
    const char* dr = rows + 16 * 1536;
    float dot = 0.f;
    #pragma unroll
    for (int z = 0; z < 4; ++z){
      const int qoff = hh * 256 + cs * 64 + z * 16;
      const int koff = 512 + g * 256 + cs * 64 + z * 16;
      const bs8 sq = *(const bs8*)(er + (qoff ^ swz));
      const bs8 dq = *(const bs8*)(dr + qoff);
      const bs8 sk = *(const bs8*)(er + (koff ^ swz));
      const bs8 dk = *(const bs8*)(dr + koff);
      #pragma unroll
      for (int m = 0; m < 8; ++m){
        const float Q = bf2f((u16)sq[m]) + bf2f((u16)dq[m]);
        const float K = bf2f((u16)sk[m]) + bf2f((u16)dk[m]);
        dot += Q * K;
      }
    }
    dot += __shfl_xor(dot, 1);
    dot += __shfl_xor(dot, 2);
    if (cs == 0) ewb[e][w] = dot * 0.0625f;
  }
  __syncthreads();

  if (tid < 4){
    float S = 0.f;
    #pragma unroll
    for (int e = 0; e < 16; ++e) S += ewb[e][tid];
    const int hh = tid >> 1, g = tid & 1;
    (g ? TB1 : TB0)[i * 544 + 512 + hh] = f2bf(S);
  } else if (tid < 34){
    TB0[i * 544 + 510 + tid] = 0;
    TB1[i * 544 + 510 + tid] = 0;
  }

  {
    const int c = tid;
    const float A1c = bf2f(*(const u16*)(rows + 16 * 1536 + 1024 + 2 * c));
    const float xi = ldf<DT>(x, i * 256 + c);
    float T0 = 0.f, T1 = 0.f, T2 = 0.f, T3 = 0.f;
    #pragma unroll
    for (int e = 0; e < 16; ++e){
      const float4 e4 = *(const float4*)&ewb[e][0];
      const float B1 = bf2f(*(const u16*)(rows + e * 1536 + ((1024 + 2 * c) ^ ((e & 7) << 4))));
      const float h = fmaxf(A1c + B1, 0.f) + xi;
      T0 += h * e4.x; T1 += h * e4.y; T2 += h * e4.z; T3 += h * e4.w;
    }
    *(u32*)(TB0 + i * 544 + 2 * c) = (u32)f2bf(T0) | ((u32)f2bf(T2) << 16);
    *(u32*)(TB1 + i * 544 + 2 * c) = (u32)f2bf(T1) | ((u32)f2bf(T3) << 16);
  }
}
__global__ __launch_bounds__(256) void edge2_kernel(
    const void* __restrict__ x, const u16* __restrict__ SP, const u16* __restrict__ DP,
    const int* __restrict__ knn, u16* __restrict__ TB0, u16* __restrict__ TB1,
    const int* __restrict__ flag)
{
  __shared__ char rows[17 * 1536];
  __shared__ float ewb[16][4];
  if (flag[0] == 0) edge2_body<0>(x, SP, DP, knn, TB0, TB1, rows, ewb);
  else              edge2_body<1>(x, SP, DP, knn, TB0, TB1, rows, ewb);
}

// ---------------- fgemm: OUT_g = TBg @ A2^T (incl. bias-S, /16) ----------
template<int DT>
__device__ __forceinline__ void fgemm_body(const u16* TB0, const u16* TB1,
                                           const u16* a2t, void* out)
{
  const int tid = threadIdx.x, wave = tid >> 6, lane = tid & 63;
  const int l15 = lane & 15, lq = lane >> 4;
  const int I0 = blockIdx.x * 64;
  const int s0 = blockIdx.y * 64;
  const int g = wave & 1, nh = wave >> 1;
  const u16* TB = g ? TB1 : TB0;
  const int nodeb = I0 + nh * 32;

  f32x4 acc[2][4];
  #pragma unroll
  for (int cf = 0; cf < 2; ++cf)
    #pragma unroll
    for (int qf = 0; qf < 4; ++qf) acc[cf][qf] = (f32x4){0.f, 0.f, 0.f, 0.f};

  #pragma unroll
  for (int ks = 0; ks < 17; ++ks){
    bs8 av[2], bv[4];
    #pragma unroll
    for (int cf = 0; cf < 2; ++cf){
      int nr = nodeb + cf * 16 + l15; if (nr > NQ - 1) nr = NQ - 1;
      av[cf] = *(const bs8*)(TB + nr * 544 + ks * 32 + lq * 8);
    }
    #pragma unroll
    for (int qf = 0; qf < 4; ++qf)
      bv[qf] = *(const bs8*)(a2t + (s0 + qf * 16 + l15) * 544 + ks * 32 + lq * 8);
    #pragma unroll
    for (int cf = 0; cf < 2; ++cf)
      #pragma unroll
      for (int qf = 0; qf < 4; ++qf)
        acc[cf][qf] = __builtin_amdgcn_mfma_f32_16x16x32_bf16(av[cf], bv[qf], acc[cf][qf], 0, 0, 0);
  }

  #pragma unroll
  for (int cf = 0; cf < 2; ++cf)
    #pragma unroll
    for (int qf = 0; qf < 4; ++qf){
      const int scol = s0 + qf * 16 + l15;
      #pragma unroll
      for (int q = 0; q < 4; ++q){
        const int node = nodeb + cf * 16 + lq * 4 + q;
        if (node < NQ){
          const float val = acc[cf][qf][q] * 0.0625f;
          if (DT == 0) ((float*)out)[node * 256 + 2 * scol + g] = val;
          else         ((u16*)out)[node * 256 + 2 * scol + g] = f2bf(val);
        }
      }
    }
}
__global__ __launch_bounds__(256) void fgemm_kernel(const u16* __restrict__ TB0, const u16* __restrict__ TB1,
                                                    const u16* __restrict__ a2t, void* __restrict__ out,
                                                    const int* __restrict__ flag)
{
  if (flag[0] == 0) fgemm_body<0>(TB0, TB1, a2t, out);
  else              fgemm_body<1>(TB0, TB1, a2t, out);
}

extern "C" void kernel_launch(void* const* d_in, const int* in_sizes, int n_in,
                              void* d_out, int out_size, void* d_ws, size_t ws_size,
                              hipStream_t stream)
{
  const void* x  = d_in[0];
  const void* W1 = d_in[1];
  const void* b1 = d_in[2];
  const void* W2 = d_in[3];
  const void* b2 = d_in[4];
  const void* Wq = d_in[5];
  const void* bq = d_in[6];
  const void* Wk = d_in[7];
  const void* bk = d_in[8];

  char* ws = (char*)d_ws;
  int*   flag  = (int*)ws;                    // 64
  u16*   xh    = (u16*)(ws + 64);             // 5,120,000
  u16*   wt    = (u16*)(ws + 5120064);        // 786,432
  u16*   a2t   = (u16*)(ws + 5906496);        // 139,264
  u16*   w2t   = (u16*)(ws + 6045760);        // 131,072 (written by prep job 6; unused)
  u16*   bwb   = (u16*)(ws + 6176832);        // 1,536
  float* n2    = (float*)(ws + 6178368);      // 40,000
  float* tauP  = (float*)(ws + 6218368);      // 40,000
  int*   gcnt  = (int*)(ws + 6258368);        // 40,000
  int*   ccnt  = (int*)(ws + 6298368);        // 40,000
  int*   knn   = (int*)(ws + 6338368);        // 640,000
  int*   cand  = (int*)(ws + 6978368);        // 1,280,000
  float* minD  = (float*)(ws + 8258368);      // 6,320,000 (window with candP)
  u64*   candP = (u64*)(ws + 8258368);        // 10,240,000
  u16*   SP    = (u16*)(ws + 18498368);       // 15,360,000
  u16*   DP    = (u16*)(ws + 33858368);       // 15,360,000
  u16*   TB0   = (u16*)(ws + 6978368);        // 10,880,000 (aliases cand+candP, dead by then)
  int*   tcnt  = (int*)(ws + 49218368);       // 640 (TB1 region; dead before edge2)
  int*   qlist = (int*)(ws + 49219008);       // 158*10000*4 = 6,320,000
  u16*   TB1   = (u16*)(ws + 49218368);       // 10,880,000 (edge2 phase only)
  // total (big path): 60,098,368 bytes
  (void)ws_size;

  detect_kernel<<<1, 256, 0, stream>>>((const u32*)x, flag);

  cvtn2_kernel<<<2500, 256, 0, stream>>>(x, xh, n2, flag);
  prep_kernel<<<8, 256, 0, stream>>>(Wq, Wk, W1, W2, bq, bk, b1, wt, w2t, bwb, flag);
  a2prep_kernel<<<128, 256, 0, stream>>>(W2, b2, a2t, flag);
  zero_kernel<<<40, 256, 0, stream>>>(gcnt, tcnt);

  gemm_fused_kernel<<<NPG + NPAIR, 256, 0, stream>>>(xh, wt, bwb, SP, DP, n2, minD);

  knn_tau_kernel<<<40, 256, 0, stream>>>(minD, tauP);
  listbuild_kernel<<<40, 256, 0, stream>>>(minD, tauP, tcnt, qlist);
  knn_scan_kernel<<<dim3(NT64, 8), 256, 0, stream>>>(xh, n2, tauP, tcnt, qlist, gcnt, candP);
  select32_kernel<<<2500, 256, 0, stream>>>(candP, gcnt, cand, ccnt);

  rescore_kernel<<<2500, 256, 0, stream>>>(x, n2, cand, ccnt, knn, flag);

  edge2_kernel<<<10000, 256, 0, stream>>>(x, SP, DP, knn, TB0, TB1, flag);
  fgemm_kernel<<<dim3(157, 2), 256, 0, stream>>>(TB0, TB1, a2t, d_out, flag);
}

// Round 21
// 408.687 us; speedup vs baseline: 1.1712x; 1.0204x over previous
//
#include <hip/hip_runtime.h>

#define NQ    10000
#define CD    256
#define KNBR  16
#define NCAND 32
#define CAP   128
#define NT64  158        // 79 tiles x 2 half-tiles of 64 cand rows
#define NPAIR 3160       // 79*80/2 upper-triangle tile pairs
#define NPG   474        // pgemm blocks (79 x 6)
#define MARGIN 2.0f

typedef short bs8 __attribute__((ext_vector_type(8)));
typedef float f32x4 __attribute__((ext_vector_type(4)));
typedef unsigned short u16;
typedef unsigned int u32;
typedef unsigned long long u64;
typedef unsigned short us4 __attribute__((ext_vector_type(4)));

__device__ __forceinline__ float bf2f(u16 u){
  union { u32 i; float f; } c; c.i = ((u32)u) << 16; return c.f;
}
__device__ __forceinline__ u16 f2bf(float f){
  union { float f; u32 i; } c; c.f = f;
  u32 u = c.i;
  u += 0x7fffu + ((u >> 16) & 1u);   // RTNE
  return (u16)(u >> 16);
}
template<int DT>
__device__ __forceinline__ float ldf(const void* p, int i){
  if (DT) return bf2f(((const u16*)p)[i]);
  return ((const float*)p)[i];
}

// ---------------- dtype detect: flag=0 f32, flag=1 bf16 ------------------
__global__ __launch_bounds__(256) void detect_kernel(const u32* __restrict__ xw, int* __restrict__ flag)
{
  __shared__ int cnt;
  if (threadIdx.x == 0) cnt = 0;
  __syncthreads();
  const u32 w = xw[threadIdx.x];
  const int e = (int)((w >> 7) & 0xff);
  if (e >= 120 && e <= 131) atomicAdd(&cnt, 1);
  __syncthreads();
  if (threadIdx.x == 0) flag[0] = (cnt >= 128) ? 1 : 0;
}

// ---------------- prep-stage bodies --------------------------------------
__device__ __forceinline__ void cvtn2_dev(const void* xin, u16* xh, float* n2, int dt, int b)
{
  const int tid = threadIdx.x, lane = tid & 63;
  const int idx = (b * 256 + tid) * 4;
  float a, bb, c, d;
  us4 r;
  if (dt == 0){
    const float4 v = *(const float4*)((const float*)xin + idx);
    a = v.x; bb = v.y; c = v.z; d = v.w;
    r[0] = f2bf(a); r[1] = f2bf(bb); r[2] = f2bf(c); r[3] = f2bf(d);
  } else {
    r = *(const us4*)((const u16*)xin + idx);
    a = bf2f((u16)r[0]); bb = bf2f((u16)r[1]); c = bf2f((u16)r[2]); d = bf2f((u16)r[3]);
  }
  *(us4*)(xh + idx) = r;
  float s = a*a + bb*bb + c*c + d*d;
  #pragma unroll
  for (int m = 1; m < 64; m <<= 1) s += __shfl_xor(s, m);
  if (lane == 0) n2[idx >> 8] = s;
}

template<int DT>
__device__ __forceinline__ void prep_body(const void* Wq, const void* Wk,
                                          const void* W1, const void* W2,
                                          const void* bq, const void* bk, const void* b1,
                                          u16* wt, u16* w2t, u16* bwb, int job)
{
  const int n = threadIdx.x;
  if (job == 7){
    bwb[n]       = f2bf(ldf<DT>(bq, n));
    bwb[256 + n] = f2bf(ldf<DT>(bk, n));
    bwb[512 + n] = f2bf(ldf<DT>(b1, n));
    return;
  }
  const void* src; int soff; u16* dst;
  switch (job){
    case 0: src = Wq; soff = 0;     dst = wt;          break;
    case 1: src = Wk; soff = 0;     dst = wt + 65536;  break;
    case 2: src = W1; soff = 65536; dst = wt + 131072; break;
    case 3: src = Wq; soff = 65536; dst = wt + 196608; break;
    case 4: src = Wk; soff = 65536; dst = wt + 262144; break;
    case 5: src = W1; soff = 0;     dst = wt + 327680; break;
    default: src = W2; soff = 0;    dst = w2t;         break;
  }
  for (int c = 0; c < 256; ++c)
    dst[n*256 + c] = f2bf(ldf<DT>(src, soff + c*256 + n));
}

template<int DT>
__device__ __forceinline__ void a2prep_body(const void* W2, const void* b2, u16* a2t, int s)
{
  const int c = threadIdx.x;
  a2t[s*544 + 2*c]     = f2bf(ldf<DT>(W2, c*256 + 2*s));
  a2t[s*544 + 2*c + 1] = f2bf(ldf<DT>(W2, c*256 + 2*s + 1));
  if (c < 2)        a2t[s*544 + 512 + c] = f2bf(ldf<DT>(b2, 2*s + c));
  else if (c < 32)  a2t[s*544 + 512 + c] = 0;
}

// ---------------- FUSED prep stage: cvtn2 | prep | a2prep | zero ---------
// blocks: [0,2500) cvtn2, [2500,2508) prep, [2508,2636) a2prep, [2636,2676) zero
__global__ __launch_bounds__(256) void prep_fused_kernel(
    const void* __restrict__ xin, u16* __restrict__ xh, float* __restrict__ n2,
    const void* __restrict__ Wq, const void* __restrict__ Wk,
    const void* __restrict__ W1, const void* __restrict__ W2,
    const void* __restrict__ bq, const void* __restrict__ bk,
    const void* __restrict__ b1, const void* __restrict__ b2,
    u16* __restrict__ wt, u16* __restrict__ w2t, u16* __restrict__ bwb,
    u16* __restrict__ a2t, int* __restrict__ gcnt, int* __restrict__ tcnt,
    const int* __restrict__ flag)
{
  const int b = blockIdx.x;
  const int dt = flag[0];
  if (b < 2500){
    cvtn2_dev(xin, xh, n2, dt, b);
  } else if (b < 2508){
    if (dt == 0) prep_body<0>(Wq, Wk, W1, W2, bq, bk, b1, wt, w2t, bwb, b - 2500);
    else         prep_body<1>(Wq, Wk, W1, W2, bq, bk, b1, wt, w2t, bwb, b - 2500);
  } else if (b < 2636){
    if (dt == 0) a2prep_body<0>(W2, b2, a2t, b - 2508);
    else         a2prep_body<1>(W2, b2, a2t, b - 2508);
  } else {
    const int i = (b - 2636) * 256 + threadIdx.x;
    if (i < NQ) gcnt[i] = 0;
    if (i < NT64) tcnt[i] = 0;
  }
}

// ---------------- pgemm body (projections as tiled GEMM) -----------------
__device__ __forceinline__ void pgemm_dev(u16* cta,
                                          const u16* __restrict__ xh,
                                          const u16* __restrict__ wt,
                                          const u16* __restrict__ bwb,
                                          u16* __restrict__ SP, u16* __restrict__ DP,
                                          int bx, int by)
{
  const int tid = threadIdx.x, wave = tid >> 6, lane = tid & 63;
  const int l15 = lane & 15, lq = lane >> 4;
  const int qg = wave & 1, cg = wave >> 1;
  const int I0 = bx * 128;

  {
    const int rloc = tid >> 5;
    const int cby  = (tid & 31) * 16;
    const int wby  = cby ^ ((rloc & 7) << 4);
    #pragma unroll
    for (int i = 0; i < 16; ++i){
      int grow = I0 + i * 8 + rloc;
      if (grow > NQ - 1) grow = NQ - 1;
      const uint4 v = *(const uint4*)(xh + grow * 256 + (cby >> 1));
      *(uint4*)((char*)cta + (i * 8 + rloc) * 512 + wby) = v;
    }
  }
  __syncthreads();

  const int crb = I0 + cg * 64 + lq * 4;

  #pragma unroll 1
  for (int jp = 0; jp < 2; ++jp){
    const int J0 = (by * 2 + jp) * 128;
    const int q0 = J0 + qg * 64;

    f32x4 acc[4][4];
    #pragma unroll
    for (int cf = 0; cf < 4; ++cf)
      #pragma unroll
      for (int qf = 0; qf < 4; ++qf)
        acc[cf][qf] = (f32x4){0.f, 0.f, 0.f, 0.f};

    #pragma unroll
    for (int ks = 0; ks < 8; ++ks){
      bs8 qv[4];
      #pragma unroll
      for (int qf = 0; qf < 4; ++qf){
        const int wc = q0 + qf * 16 + l15;
        qv[qf] = *(const bs8*)(wt + wc * 256 + ks * 32 + lq * 8);
      }
      bs8 cv[4];
      #pragma unroll
      for (int cf = 0; cf < 4; ++cf){
        const int row = cg * 64 + cf * 16 + l15;
        const int cby = (ks * 64 + lq * 16) ^ ((l15 & 7) << 4);
        cv[cf] = *(const bs8*)((const char*)cta + row * 512 + cby);
      }
      #pragma unroll
      for (int cf = 0; cf < 4; ++cf)
        #pragma unroll
        for (int qf = 0; qf < 4; ++qf)
          acc[cf][qf] = __builtin_amdgcn_mfma_f32_16x16x32_bf16(cv[cf], qv[qf], acc[cf][qf], 0, 0, 0);
    }

    #pragma unroll
    for (int qf = 0; qf < 4; ++qf){
      const int c = q0 + qf * 16 + l15;
      const float bias = (c >= 768) ? bf2f(bwb[c - 768]) : 0.f;
      #pragma unroll
      for (int cf = 0; cf < 4; ++cf){
        #pragma unroll
        for (int q = 0; q < 4; ++q){
          const int node = crb + cf * 16 + q;
          if (node < NQ){
            const u16 v = f2bf(acc[cf][qf][q] + bias);
            if (c < 768) SP[node * 768 + c] = v;
            else         DP[node * 768 + (c - 768)] = v;
          }
        }
      }
    }
    __syncthreads();
  }
}

// ---------------- knn_gemm body (one (I,J) pair) -------------------------
__device__ __forceinline__ void knngemm_dev(u16* cta,
                                            const u16* __restrict__ xh,
                                            const float* __restrict__ n2,
                                            float* __restrict__ minD, int p)
{
  const int tid = threadIdx.x, wave = tid >> 6, lane = tid & 63;
  const int l15 = lane & 15, lq = lane >> 4;
  const int qg = wave & 1, cg = wave >> 1;

  int I = 0, s = 0;
  while (s + (79 - I) <= p){ s += 79 - I; ++I; }
  const int J = I + (p - s);
  const int I0 = I * 128, J0 = J * 128;

  {
    const int rloc = tid >> 5;
    const int cby  = (tid & 31) * 16;
    const int wby  = cby ^ ((rloc & 7) << 4);
    #pragma unroll
    for (int i = 0; i < 16; ++i){
      int grow = I0 + i * 8 + rloc;
      if (grow > NQ - 1) grow = NQ - 1;
      const uint4 v = *(const uint4*)(xh + grow * 256 + (cby >> 1));
      *(uint4*)((char*)cta + (i * 8 + rloc) * 512 + wby) = v;
    }
  }
  __syncthreads();

  const int crb = I0 + cg * 64 + lq * 4;
  const int q0 = J0 + qg * 64;

  f32x4 acc[4][4];
  #pragma unroll
  for (int cf = 0; cf < 4; ++cf)
    #pragma unroll
    for (int qf = 0; qf < 4; ++qf)
      acc[cf][qf] = (f32x4){0.f, 0.f, 0.f, 0.f};

  #pragma unroll
  for (int ks = 0; ks < 8; ++ks){
    bs8 qv[4];
    #pragma unroll
    for (int qf = 0; qf < 4; ++qf){
      int qr = q0 + qf * 16 + l15; if (qr > NQ - 1) qr = NQ - 1;
      qv[qf] = *(const bs8*)(xh + qr * 256 + ks * 32 + lq * 8);
    }
    bs8 cv[4];
    #pragma unroll
    for (int cf = 0; cf < 4; ++cf){
      const int row = cg * 64 + cf * 16 + l15;
      const int cby = (ks * 64 + lq * 16) ^ ((l15 & 7) << 4);
      cv[cf] = *(const bs8*)((const char*)cta + row * 512 + cby);
    }
    #pragma unroll
    for (int cf = 0; cf < 4; ++cf)
      #pragma unroll
      for (int qf = 0; qf < 4; ++qf)
        acc[cf][qf] = __builtin_amdgcn_mfma_f32_16x16x32_bf16(cv[cf], qv[qf], acc[cf][qf], 0, 0, 0);
  }

  float n2v[4][4];
  #pragma unroll
  for (int cf = 0; cf < 4; ++cf)
    #pragma unroll
    for (int q = 0; q < 4; ++q){
      int r = crb + cf * 16 + q; if (r > NQ - 1) r = NQ - 1;
      n2v[cf][q] = n2[r];
    }
  float n2c[4];
  #pragma unroll
  for (int qf = 0; qf < 4; ++qf){
    int c = q0 + qf * 16 + l15; if (c > NQ - 1) c = NQ - 1;
    n2c[qf] = n2[c];
  }

  // normal: min over rows -> minD[I-half][col]
  #pragma unroll
  for (int qf = 0; qf < 4; ++qf){
    const int qc = q0 + qf * 16 + l15;
    float m = __builtin_inff();
    #pragma unroll
    for (int cf = 0; cf < 4; ++cf)
      #pragma unroll
      for (int q = 0; q < 4; ++q){
        const int r = crb + cf * 16 + q;
        const float dd = n2v[cf][q] - 2.f * acc[cf][qf][q];
        const bool ok = (r < NQ) && (r != qc);
        m = fminf(m, ok ? dd : __builtin_inff());
      }
    m = fminf(m, __shfl_xor(m, 16));
    m = fminf(m, __shfl_xor(m, 32));
    if (lane < 16){
      const int qs = q0 + qf * 16 + lane;
      if (qs < NQ) minD[(I * 2 + cg) * NQ + qs] = m;
    }
  }
  // transposed (off-diagonal only): min over cols -> minD[J-half][row]
  if (I != J){
    #pragma unroll
    for (int cf = 0; cf < 4; ++cf)
      #pragma unroll
      for (int q = 0; q < 4; ++q){
        float m = __builtin_inff();
        #pragma unroll
        for (int qf = 0; qf < 4; ++qf){
          const int c = q0 + qf * 16 + l15;
          const float v = n2c[qf] - 2.f * acc[cf][qf][q];
          m = fminf(m, (c < NQ) ? v : __builtin_inff());
        }
        m = fminf(m, __shfl_xor(m, 1));
        m = fminf(m, __shfl_xor(m, 2));
        m = fminf(m, __shfl_xor(m, 4));
        m = fminf(m, __shfl_xor(m, 8));
        const int r = crb + cf * 16 + q;
        if (l15 == 0 && r < NQ) minD[(J * 2 + qg) * NQ + r] = m;
      }
  }
}

// ---------------- FUSED: pgemm (474 blocks) + knn_gemm (3160 pairs) ------
__global__ __launch_bounds__(256) void gemm_fused_kernel(
    const u16* __restrict__ xh, const u16* __restrict__ wt,
    const u16* __restrict__ bwb, u16* __restrict__ SP, u16* __restrict__ DP,
    const float* __restrict__ n2, float* __restrict__ minD)
{
  __shared__ u16 cta[128 * 256];   // 64 KB, shared by both bodies
  const int b = blockIdx.x;
  if (b < NPG) pgemm_dev(cta, xh, wt, bwb, SP, DP, b % 79, b / 79);
  else         knngemm_dev(cta, xh, n2, minD, b - NPG);
}

// ---------------- tau: 16th-smallest tile-min + margin -------------------
__global__ __launch_bounds__(256) void knn_tau_kernel(const float* __restrict__ minD,
                                                      float* __restrict__ tauP)
{
  const int q = blockIdx.x * 256 + threadIdx.x;
  if (q >= NQ) return;
  float ld[16];
  #pragma unroll
  for (int s = 0; s < 16; ++s) ld[s] = __builtin_inff();
  for (int t = 0; t < NT64; ++t){
    float v = minD[t * NQ + q];
    if (v < ld[15]){
      #pragma unroll
      for (int s = 0; s < 16; ++s){
        const bool cmp = v < ld[s];
        const float tv = ld[s];
        ld[s] = cmp ? v : tv;
        v = cmp ? tv : v;
      }
    }
  }
  tauP[q] = ld[15] + MARGIN;
}

// ---------------- build per-tile query lists (wave-per-tile, NO atomics) -
__global__ __launch_bounds__(256) void listbuild_kernel(const float* __restrict__ minD,
                                                        const float* __restrict__ tauP,
                                                        int* __restrict__ tcnt,
                                                        int* __restrict__ qlist)
{
  const int wave = threadIdx.x >> 6, lane = threadIdx.x & 63;
  const int t = blockIdx.x * 4 + wave;
  if (t >= NT64) return;
  const float* row = minD + (size_t)t * NQ;
  int base = 0;
  #pragma unroll 1
  for (int c = 0; c < 157; ++c){
    const int q = c * 64 + lane;
    const bool f = (q < NQ) && (row[q] < tauP[q]);
    const u64 mask = __ballot(f);
    if (f){
      const int off = (int)__popcll(mask & ((1ull << lane) - 1ull));
      qlist[t * NQ + base + off] = q;
    }
    base += (int)__popcll(mask);
  }
  if (lane == 0) tcnt[t] = base;
}

// ---------------- PASS C replacement: tile-centric pruned scan -----------
__global__ __launch_bounds__(256) void knn_scan_kernel(
    const u16* __restrict__ xh, const float* __restrict__ n2,
    const float* __restrict__ tauP, const int* __restrict__ tcnt,
    const int* __restrict__ qlist, int* __restrict__ gcnt,
    u64* __restrict__ candP)
{
  __shared__ u16 cta[64 * 256];   // 32 KB
  const int t = blockIdx.x;
  const int chunk = blockIdx.y;
  const int tid = threadIdx.x, wave = tid >> 6, lane = tid & 63;
  const int l15 = lane & 15, lq = lane >> 4;
  const int I0 = t * 64;

  {
    const int rloc = tid >> 5;
    const int cby  = (tid & 31) * 16;
    const int wby  = cby ^ ((rloc & 7) << 4);
    #pragma unroll
    for (int i = 0; i < 8; ++i){
      int grow = I0 + i * 8 + rloc;
      if (grow > NQ - 1) grow = NQ - 1;
      const uint4 v = *(const uint4*)(xh + grow * 256 + (cby >> 1));
      *(uint4*)((char*)cta + (i * 8 + rloc) * 512 + wby) = v;
    }
  }
  __syncthreads();

  float n2v[4][4];
  #pragma unroll
  for (int cf = 0; cf < 4; ++cf)
    #pragma unroll
    for (int q = 0; q < 4; ++q){
      int r = I0 + cf * 16 + lq * 4 + q; if (r > NQ - 1) r = NQ - 1;
      n2v[cf][q] = n2[r];
    }

  const int cnt = tcnt[t];
  const int ngr = (cnt + 15) >> 4;

  #pragma unroll 1
  for (int gi = chunk * 4 + wave; gi < ngr; gi += 32){
    const int qi = gi * 16 + l15;
    const bool qok = qi < cnt;
    const int qc = qok ? qlist[t * NQ + qi] : 0;

    bs8 qv[8];
    #pragma unroll
    for (int ks = 0; ks < 8; ++ks)
      qv[ks] = *(const bs8*)(xh + qc * 256 + ks * 32 + lq * 8);

    f32x4 acc[4];
    #pragma unroll
    for (int cf = 0; cf < 4; ++cf) acc[cf] = (f32x4){0.f, 0.f, 0.f, 0.f};

    #pragma unroll
    for (int ks = 0; ks < 8; ++ks){
      const int cby = (ks * 64 + lq * 16) ^ ((l15 & 7) << 4);
      #pragma unroll
      for (int cf = 0; cf < 4; ++cf){
        const bs8 cv = *(const bs8*)((const char*)cta + (cf * 16 + l15) * 512 + cby);
        acc[cf] = __builtin_amdgcn_mfma_f32_16x16x32_bf16(cv, qv[ks], acc[cf], 0, 0, 0);
      }
    }

    const float tq = qok ? tauP[qc] : -__builtin_inff();
    #pragma unroll
    for (int cf = 0; cf < 4; ++cf){
      #pragma unroll
      for (int q = 0; q < 4; ++q){
        const int r = I0 + cf * 16 + lq * 4 + q;
        const float dd = n2v[cf][q] - 2.f * acc[cf][q];
        const bool dump = qok && (r < NQ) && (r != qc) && (dd < tq);
        if (dump){
          const int pos = atomicAdd(gcnt + qc, 1);
          if (pos < CAP)
            candP[qc * CAP + pos] =
                (((u64)__float_as_uint(dd + 1024.f)) << 32) | (u32)r;
        }
      }
    }
  }
}

// ---------------- FUSED select top-32 + exact rescore -> top-16 ----------
// Wave per query. Select ranks candidates in LDS (no global cand/ccnt),
// rescore reads the sorted list straight from LDS. Same keys/tie-breaks as
// the split kernels -> knn bit-identical.
template<int DT>
__device__ __forceinline__ void selres_body(const u64* candP, const int* gcnt,
                                            const void* x, const float* n2,
                                            int* knn, u64 (*sl)[CAP], int (*scand)[NCAND])
{
  const int tid = threadIdx.x, wave = tid >> 6, lane = tid & 63;
  const int q = blockIdx.x * 4 + wave;
  int cnt = gcnt[q]; if (cnt > CAP) cnt = CAP;
  const u64* src = candP + (size_t)q * CAP;
  for (int c = lane; c < cnt; c += 64) sl[wave][c] = src[c];
  __syncthreads();
  for (int c = lane; c < cnt; c += 64){
    const u64 me = sl[wave][c];
    int rank = 0;
    for (int o = 0; o < cnt; ++o){
      const u64 ov = sl[wave][o];
      rank += (ov < me || (ov == me && o < c)) ? 1 : 0;
    }
    if (rank < NCAND) scand[wave][rank] = (int)(me & 0xffffffffu);
  }
  __syncthreads();
  const int cc = (cnt < NCAND) ? cnt : NCAND;

  const int base = q * CD + lane * 4;
  float xi0, xi1, xi2, xi3;
  if (DT == 0){
    const float4 v = *(const float4*)((const float*)x + base);
    xi0 = v.x; xi1 = v.y; xi2 = v.z; xi3 = v.w;
  } else {
    const u32* p = (const u32*)x + (base >> 1);
    const u32 w0 = p[0], w1 = p[1];
    xi0 = bf2f((u16)(w0 & 0xffff)); xi1 = bf2f((u16)(w0 >> 16));
    xi2 = bf2f((u16)(w1 & 0xffff)); xi3 = bf2f((u16)(w1 >> 16));
  }
  const float n2i = n2[q];
  const int cown = lane & 31;
  float myd = __builtin_inff(); int myi = NQ + lane;
  for (int c = 0; c < NCAND; ++c){
    const int j = (c < cc) ? scand[wave][c] : 0;
    const int jb = j * CD + lane * 4;
    float a0, a1, a2, a3;
    if (DT == 0){
      const float4 v = *(const float4*)((const float*)x + jb);
      a0 = v.x; a1 = v.y; a2 = v.z; a3 = v.w;
    } else {
      const u32* p = (const u32*)x + (jb >> 1);
      const u32 w0 = p[0], w1 = p[1];
      a0 = bf2f((u16)(w0 & 0xffff)); a1 = bf2f((u16)(w0 >> 16));
      a2 = bf2f((u16)(w1 & 0xffff)); a3 = bf2f((u16)(w1 >> 16));
    }
    float pdt = xi0*a0 + xi1*a1 + xi2*a2 + xi3*a3;
    #pragma unroll
    for (int m = 1; m < 64; m <<= 1) pdt += __shfl_xor(pdt, m);
    const float d = n2i + n2[j] - 2.f * pdt;
    if (c == cown && c < cc){ myd = d; myi = j; }
  }
  int rank = 0;
  #pragma unroll
  for (int m = 1; m < NCAND; ++m){
    int oc = cown + m; if (oc >= NCAND) oc -= NCAND;
    const float od = __shfl(myd, oc);
    const int   oi = __shfl(myi, oc);
    rank += (od < myd || (od == myd && oi < myi)) ? 1 : 0;
  }
  if (lane < NCAND && rank < KNBR) knn[q * KNBR + rank] = myi;
}
__global__ __launch_bounds__(256) void selres_kernel(const u64* __restrict__ candP,
                                                     const int* __restrict__ gcnt,
                                                     const void* __restrict__ x,
                                                     const float* __restrict__ n2,
                                                     int* __restrict__ knn,
                                                     const int* __restrict__ flag)
{
  __shared__ u64 sl[4][CAP];
  __shared__ int scand[4][NCAND];
  if (flag[0] == 0) selres_body<0>(candP, gcnt, x, n2, knn, sl, scand);
  else              selres_body<1>(candP, gcnt, x, n2, knn, sl, scand);
}

// ---------------- edge2: block-per-node, LDS-staged ----------------------
template<int DT>
__device__ __forceinline__ void edge2_body(const void* x, const u16* SP, const u16* DP,
                                           const int* knn, u16* TB0, u16* TB1,
                                           char* rows, float (*ewb)[4])
{
  const int tid = threadIdx.x;
  const int i = blockIdx.x;

  {
    const int e = tid >> 4, six = tid & 15;
    const int j = knn[i * KNBR + e];
    const int swz = (e & 7) << 4;
    #pragma unroll
    for (int ch = 0; ch < 6; ++ch){
      const uint4 v = *(const uint4*)(SP + j * 768 + ch * 128 + six * 8);
      *(uint4*)(rows + e * 1536 + ((ch * 256 + six * 16) ^ swz)) = v;
    }
    if (tid < 96){
      const uint4 v = *(const uint4*)(DP + i * 768 + tid * 8);
      *(uint4*)(rows + 16 * 1536 + tid * 16) = v;
    }
  }
  __syncthreads();

  {
    const int w = tid >> 6, e = (tid >> 2) & 15, cs = tid & 3;
    const int hh = w >> 1, g = w & 1;
    const int swz = (e & 7) << 4;
    const char* er = rows + e * 1536;
    const char* dr = rows + 16 * 1536;
    float dot = 0.f;
    #pragma unroll
    for (int z = 0; z < 4; ++z){
      const int qoff = hh * 256 + cs * 64 + z * 16;
      const int koff = 512 + g * 256 + cs * 64 + z * 16;
      const bs8 sq = *(const bs8*)(er + (qoff ^ swz));
      const bs8 dq = *(const bs8*)(dr + qoff);
      const bs8 sk = *(const bs8*)(er + (koff ^ swz));
      const bs8 dk = *(const bs8*)(dr + koff);
      #pragma unroll
      for (int m = 0; m < 8; ++m){
        const float Q = bf2f((u16)sq[m]) + bf2f((u16)dq[m]);
        const float K = bf2f((u16)sk[m]) + bf2f((u16)dk[m]);
        dot += Q * K;
      }
    }
    dot += __shfl_xor(dot, 1);
    dot += __shfl_xor(dot, 2);
    if (cs == 0) ewb[e][w] = dot * 0.0625f;
  }
  __syncthreads();

  if (tid < 4){
    float S = 0.f;
    #pragma unroll
    for (int e = 0; e < 16; ++e) S += ewb[e][tid];
    const int hh = tid >> 1, g = tid & 1;
    (g ? TB1 : TB0)[i * 544 + 512 + hh] = f2bf(S);
  } else if (tid < 34){
    TB0[i * 544 + 510 + tid] = 0;
    TB1[i * 544 + 510 + tid] = 0;
  }

  {
    const int c = tid;
    const float A1c = bf2f(*(const u16*)(rows + 16 * 1536 + 1024 + 2 * c));
    const float xi = ldf<DT>(x, i * 256 + c);
    float T0 = 0.f, T1 = 0.f, T2 = 0.f, T3 = 0.f;
    #pragma unroll
    for (int e = 0; e < 16; ++e){
      const float4 e4 = *(const float4*)&ewb[e][0];
      const float B1 = bf2f(*(const u16*)(rows + e * 1536 + ((1024 + 2 * c) ^ ((e & 7) << 4))));
      const float h = fmaxf(A1c + B1, 0.f) + xi;
      T0 += h * e4.x; T1 += h * e4.y; T2 += h * e4.z; T3 += h * e4.w;
    }
    *(u32*)(TB0 + i * 544 + 2 * c) = (u32)f2bf(T0) | ((u32)f2bf(T2) << 16);
    *(u32*)(TB1 + i * 544 + 2 * c) = (u32)f2bf(T1) | ((u32)f2bf(T3) << 16);
  }
}
__global__ __launch_bounds__(256) void edge2_kernel(
    const void* __restrict__ x, const u16* __restrict__ SP, const u16* __restrict__ DP,
    const int* __restrict__ knn, u16* __restrict__ TB0, u16* __restrict__ TB1,
    const int* __restrict__ flag)
{
  __shared__ char rows[17 * 1536];
  __shared__ float ewb[16][4];
  if (flag[0] == 0) edge2_body<0>(x, SP, DP, knn, TB0, TB1, rows, ewb);
  else              edge2_body<1>(x, SP, DP, knn, TB0, TB1, rows, ewb);
}

// ---------------- fgemm: OUT_g = TBg @ A2^T (incl. bias-S, /16) ----------
template<int DT>
__device__ __forceinline__ void fgemm_body(const u16* TB0, const u16* TB1,
                                           const u16* a2t, void* out)
{
  const int tid = threadIdx.x, wave = tid >> 6, lane = tid & 63;
  const int l15 = lane & 15, lq = lane >> 4;
  const int I0 = blockIdx.x * 64;
  const int s0 = blockIdx.y * 64;
  const int g = wave & 1, nh = wave >> 1;
  const u16* TB = g ? TB1 : TB0;
  const int nodeb = I0 + nh * 32;

  f32x4 acc[2][4];
  #pragma unroll
  for (int cf = 0; cf < 2; ++cf)
    #pragma unroll
    for (int qf = 0; qf < 4; ++qf) acc[cf][qf] = (f32x4){0.f, 0.f, 0.f, 0.f};

  #pragma unroll
  for (int ks = 0; ks < 17; ++ks){
    bs8 av[2], bv[4];
    #pragma unroll
    for (int cf = 0; cf < 2; ++cf){
      int nr = nodeb + cf * 16 + l15; if (nr > NQ - 1) nr = NQ - 1;
      av[cf] = *(const bs8*)(TB + nr * 544 + ks * 32 + lq * 8);
    }
    #pragma unroll
    for (int qf = 0; qf < 4; ++qf)
      bv[qf] = *(const bs8*)(a2t + (s0 + qf * 16 + l15) * 544 + ks * 32 + lq * 8);
    #pragma unroll
    for (int cf = 0; cf < 2; ++cf)
      #pragma unroll
      for (int qf = 0; qf < 4; ++qf)
        acc[cf][qf] = __builtin_amdgcn_mfma_f32_16x16x32_bf16(av[cf], bv[qf], acc[cf][qf], 0, 0, 0);
  }

  #pragma unroll
  for (int cf = 0; cf < 2; ++cf)
    #pragma unroll
    for (int qf = 0; qf < 4; ++qf){
      const int scol = s0 + qf * 16 + l15;
      #pragma unroll
      for (int q = 0; q < 4; ++q){
        const int node = nodeb + cf * 16 + lq * 4 + q;
        if (node < NQ){
          const float val = acc[cf][qf][q] * 0.0625f;
          if (DT == 0) ((float*)out)[node * 256 + 2 * scol + g] = val;
          else         ((u16*)out)[node * 256 + 2 * scol + g] = f2bf(val);
        }
      }
    }
}
__global__ __launch_bounds__(256) void fgemm_kernel(const u16* __restrict__ TB0, const u16* __restrict__ TB1,
                                                    const u16* __restrict__ a2t, void* __restrict__ out,
                                                    const int* __restrict__ flag)
{
  if (flag[0] == 0) fgemm_body<0>(TB0, TB1, a2t, out);
  else              fgemm_body<1>(TB0, TB1, a2t, out);
}

extern "C" void kernel_launch(void* const* d_in, const int* in_sizes, int n_in,
                              void* d_out, int out_size, void* d_ws, size_t ws_size,
                              hipStream_t stream)
{
  const void* x  = d_in[0];
  const void* W1 = d_in[1];
  const void* b1 = d_in[2];
  const void* W2 = d_in[3];
  const void* b2 = d_in[4];
  const void* Wq = d_in[5];
  const void* bq = d_in[6];
  const void* Wk = d_in[7];
  const void* bk = d_in[8];

  char* ws = (char*)d_ws;
  int*   flag  = (int*)ws;                    // 64
  u16*   xh    = (u16*)(ws + 64);             // 5,120,000
  u16*   wt    = (u16*)(ws + 5120064);        // 786,432
  u16*   a2t   = (u16*)(ws + 5906496);        // 139,264
  u16*   w2t   = (u16*)(ws + 6045760);        // 131,072 (written by prep job 6; unused)
  u16*   bwb   = (u16*)(ws + 6176832);        // 1,536
  float* n2    = (float*)(ws + 6178368);      // 40,000
  float* tauP  = (float*)(ws + 6218368);      // 40,000
  int*   gcnt  = (int*)(ws + 6258368);        // 40,000
  int*   ccnt  = (int*)(ws + 6298368);        // 40,000 (unused after fusion)
  int*   knn   = (int*)(ws + 6338368);        // 640,000
  int*   cand  = (int*)(ws + 6978368);        // 1,280,000 (unused after fusion)
  float* minD  = (float*)(ws + 8258368);      // 6,320,000 (window with candP)
  u64*   candP = (u64*)(ws + 8258368);        // 10,240,000
  u16*   SP    = (u16*)(ws + 18498368);       // 15,360,000
  u16*   DP    = (u16*)(ws + 33858368);       // 15,360,000
  u16*   TB0   = (u16*)(ws + 6978368);        // 10,880,000 (aliases cand+candP, dead by then)
  int*   tcnt  = (int*)(ws + 49218368);       // 640 (TB1 region; dead before edge2)
  int*   qlist = (int*)(ws + 49219008);       // 158*10000*4 = 6,320,000
  u16*   TB1   = (u16*)(ws + 49218368);       // 10,880,000 (edge2 phase only)
  // total (big path): 60,098,368 bytes
  (void)ws_size; (void)ccnt; (void)cand;

  detect_kernel<<<1, 256, 0, stream>>>((const u32*)x, flag);

  prep_fused_kernel<<<2676, 256, 0, stream>>>(x, xh, n2, Wq, Wk, W1, W2,
                                              bq, bk, b1, b2, wt, w2t, bwb,
                                              a2t, gcnt, tcnt, flag);

  gemm_fused_kernel<<<NPG + NPAIR, 256, 0, stream>>>(xh, wt, bwb, SP, DP, n2, minD);

  knn_tau_kernel<<<40, 256, 0, stream>>>(minD, tauP);
  listbuild_kernel<<<40, 256, 0, stream>>>(minD, tauP, tcnt, qlist);
  knn_scan_kernel<<<dim3(NT64, 8), 256, 0, stream>>>(xh, n2, tauP, tcnt, qlist, gcnt, candP);

  selres_kernel<<<2500, 256, 0, stream>>>(candP, gcnt, x, n2, knn, flag);

  edge2_kernel<<<10000, 256, 0, stream>>>(x, SP, DP, knn, TB0, TB1, flag);
  fgemm_kernel<<<dim3(157, 2), 256, 0, stream>>>(TB0, TB1, a2t, d_out, flag);
}